// Round 1
// baseline (12798.228 us; speedup 1.0000x reference)
//
#include <hip/hip_runtime.h>
#include <cstddef>

// ---------------------------------------------------------------- constants
constexpr int NB   = 8;     // batch
constexpr int SEQ  = 1024;  // sequence length
constexpr int DIM  = 512;   // model dim
constexpr int NL   = 6;     // layers
constexpr int NH   = 8;     // heads
constexpr int HDIM = 64;    // head dim
constexpr int ROWS = NB * SEQ;               // 8192
constexpr size_t BSD = (size_t)ROWS * DIM;   // 4,194,304 elements per (r or i) tensor

__device__ __forceinline__ void f4a(const float4 v, float* a) {
    a[0] = v.x; a[1] = v.y; a[2] = v.z; a[3] = v.w;
}
__device__ __forceinline__ float4 a4f(const float* a) {
    float4 v; v.x = a[0]; v.y = a[1]; v.z = a[2]; v.w = a[3]; return v;
}

// ---------------------------------------------------------------- complex GEMM
//  Yr + iYi = (Xr + iXi) @ (Wr + iWi)^T + (br + i bi);  X:[8192][512], W:[512][512]
//  Tiles: BM=64, BN=64, BK=16; 256 threads; each thread 4x4 complex outputs.
constexpr int BM = 64, BN = 64, BK = 16;

template <bool RELU>
__global__ __launch_bounds__(256)
void cgemm_kernel(const float* __restrict__ Xr, const float* __restrict__ Xi,
                  const float* __restrict__ Wr, const float* __restrict__ Wi,
                  const float* __restrict__ Br, const float* __restrict__ Bi,
                  float* __restrict__ Yr, float* __restrict__ Yi)
{
    constexpr int K = DIM, N = DIM;
    __shared__ __align__(16) float Xs_r[BK][BM + 4];
    __shared__ __align__(16) float Xs_i[BK][BM + 4];
    __shared__ __align__(16) float Ws_r[BK][BN + 4];
    __shared__ __align__(16) float Ws_i[BK][BN + 4];

    const int t  = threadIdx.x;
    const int tx = t & 15;        // n direction (x4)
    const int ty = t >> 4;        // m direction (x4)
    const int m0 = blockIdx.y * BM;
    const int n0 = blockIdx.x * BN;
    const int lr = t >> 2;        // 0..63: row within tile for loading
    const int lc = (t & 3) * 4;   // 0,4,8,12: k-chunk within tile

    float accr[4][4] = {{0.f}}, acci[4][4] = {{0.f}};

    const float* gx_r = &Xr[(size_t)(m0 + lr) * K + lc];
    const float* gx_i = &Xi[(size_t)(m0 + lr) * K + lc];
    const float* gw_r = &Wr[(size_t)(n0 + lr) * K + lc];
    const float* gw_i = &Wi[(size_t)(n0 + lr) * K + lc];

    for (int k0 = 0; k0 < K; k0 += BK) {
        const float4 xr4 = *(const float4*)(gx_r + k0);
        const float4 xi4 = *(const float4*)(gx_i + k0);
        const float4 wr4 = *(const float4*)(gw_r + k0);
        const float4 wi4 = *(const float4*)(gw_i + k0);
        __syncthreads();
        Xs_r[lc+0][lr]=xr4.x; Xs_r[lc+1][lr]=xr4.y; Xs_r[lc+2][lr]=xr4.z; Xs_r[lc+3][lr]=xr4.w;
        Xs_i[lc+0][lr]=xi4.x; Xs_i[lc+1][lr]=xi4.y; Xs_i[lc+2][lr]=xi4.z; Xs_i[lc+3][lr]=xi4.w;
        Ws_r[lc+0][lr]=wr4.x; Ws_r[lc+1][lr]=wr4.y; Ws_r[lc+2][lr]=wr4.z; Ws_r[lc+3][lr]=wr4.w;
        Ws_i[lc+0][lr]=wi4.x; Ws_i[lc+1][lr]=wi4.y; Ws_i[lc+2][lr]=wi4.z; Ws_i[lc+3][lr]=wi4.w;
        __syncthreads();

        #pragma unroll
        for (int k = 0; k < BK; ++k) {
            float ar[4], ai[4], ur[4], ui[4];
            f4a(*(const float4*)&Xs_r[k][ty * 4], ar);
            f4a(*(const float4*)&Xs_i[k][ty * 4], ai);
            f4a(*(const float4*)&Ws_r[k][tx * 4], ur);
            f4a(*(const float4*)&Ws_i[k][tx * 4], ui);
            #pragma unroll
            for (int jm = 0; jm < 4; ++jm) {
                #pragma unroll
                for (int jn = 0; jn < 4; ++jn) {
                    accr[jm][jn] = fmaf(ar[jm], ur[jn], accr[jm][jn]);
                    accr[jm][jn] = fmaf(-ai[jm], ui[jn], accr[jm][jn]);
                    acci[jm][jn] = fmaf(ar[jm], ui[jn], acci[jm][jn]);
                    acci[jm][jn] = fmaf(ai[jm], ur[jn], acci[jm][jn]);
                }
            }
        }
    }

    float br_[4], bi_[4];
    f4a(*(const float4*)&Br[n0 + tx * 4], br_);
    f4a(*(const float4*)&Bi[n0 + tx * 4], bi_);

    #pragma unroll
    for (int jm = 0; jm < 4; ++jm) {
        float outr[4], outi[4];
        #pragma unroll
        for (int jn = 0; jn < 4; ++jn) {
            float vr = accr[jm][jn] + br_[jn];
            float vi = acci[jm][jn] + bi_[jn];
            if (RELU) { vr = fmaxf(vr, 0.f); vi = fmaxf(vi, 0.f); }
            outr[jn] = vr; outi[jn] = vi;
        }
        const size_t o = (size_t)(m0 + ty * 4 + jm) * N + n0 + tx * 4;
        *(float4*)&Yr[o] = a4f(outr);
        *(float4*)&Yi[o] = a4f(outi);
    }
}

// ---------------------------------------------------------------- attention
//  logits = (qr.kr + qi.ki) * hd^-0.5 ; softmax over keys ; o = A@v (r,i)
//  One block per (b, h, 32-query tile). Writes output IN PLACE over Q.
constexpr int QB = 32, KBT = 32;

__global__ __launch_bounds__(256)
void attn_kernel(float* __restrict__ Qr, float* __restrict__ Qi,
                 const float* __restrict__ Kr, const float* __restrict__ Ki,
                 const float* __restrict__ Vr, const float* __restrict__ Vi)
{
    __shared__ __align__(16) float Qs_r[QB][HDIM + 4];
    __shared__ __align__(16) float Qs_i[QB][HDIM + 4];
    __shared__ __align__(16) float Ks_r[KBT][HDIM + 4];
    __shared__ __align__(16) float Ks_i[KBT][HDIM + 4];
    __shared__ __align__(16) float Vs_r[KBT][HDIM];
    __shared__ __align__(16) float Vs_i[KBT][HDIM];
    __shared__ __align__(16) float Ss[QB][KBT + 1];

    const int t   = threadIdx.x;
    const int q   = t >> 3;        // 0..31 query within tile
    const int sub = t & 7;         // 0..7  worker within query
    const int q0  = blockIdx.x * QB;
    const int hh  = blockIdx.y;
    const int bb  = blockIdx.z;
    const size_t base = ((size_t)bb * SEQ) * DIM + (size_t)hh * HDIM;
    const float scale = 0.125f;    // HDIM^-0.5

    {   // load Q tile (rows q0..q0+31, 64 dims)
        const int row = t >> 3, col = (t & 7) * 8;
        const size_t g = base + (size_t)(q0 + row) * DIM + col;
        float4 a0 = *(const float4*)&Qr[g];
        float4 a1 = *(const float4*)&Qr[g + 4];
        float4 b0 = *(const float4*)&Qi[g];
        float4 b1 = *(const float4*)&Qi[g + 4];
        Qs_r[row][col+0]=a0.x; Qs_r[row][col+1]=a0.y; Qs_r[row][col+2]=a0.z; Qs_r[row][col+3]=a0.w;
        Qs_r[row][col+4]=a1.x; Qs_r[row][col+5]=a1.y; Qs_r[row][col+6]=a1.z; Qs_r[row][col+7]=a1.w;
        Qs_i[row][col+0]=b0.x; Qs_i[row][col+1]=b0.y; Qs_i[row][col+2]=b0.z; Qs_i[row][col+3]=b0.w;
        Qs_i[row][col+4]=b1.x; Qs_i[row][col+5]=b1.y; Qs_i[row][col+6]=b1.z; Qs_i[row][col+7]=b1.w;
    }

    float m_run = -1e30f, l_run = 0.f;
    float o_r[8] = {0.f}, o_i[8] = {0.f};

    for (int k0 = 0; k0 < SEQ; k0 += KBT) {
        __syncthreads();  // Q visible (iter 0); prior-iter LDS reads done
        {   // load K/V tiles
            const int row = t >> 3, col = (t & 7) * 8;
            const size_t g = base + (size_t)(k0 + row) * DIM + col;
            float4 a0 = *(const float4*)&Kr[g];
            float4 a1 = *(const float4*)&Kr[g + 4];
            float4 b0 = *(const float4*)&Ki[g];
            float4 b1 = *(const float4*)&Ki[g + 4];
            Ks_r[row][col+0]=a0.x; Ks_r[row][col+1]=a0.y; Ks_r[row][col+2]=a0.z; Ks_r[row][col+3]=a0.w;
            Ks_r[row][col+4]=a1.x; Ks_r[row][col+5]=a1.y; Ks_r[row][col+6]=a1.z; Ks_r[row][col+7]=a1.w;
            Ks_i[row][col+0]=b0.x; Ks_i[row][col+1]=b0.y; Ks_i[row][col+2]=b0.z; Ks_i[row][col+3]=b0.w;
            Ks_i[row][col+4]=b1.x; Ks_i[row][col+5]=b1.y; Ks_i[row][col+6]=b1.z; Ks_i[row][col+7]=b1.w;
            *(float4*)&Vs_r[row][col]     = *(const float4*)&Vr[g];
            *(float4*)&Vs_r[row][col + 4] = *(const float4*)&Vr[g + 4];
            *(float4*)&Vs_i[row][col]     = *(const float4*)&Vi[g];
            *(float4*)&Vs_i[row][col + 4] = *(const float4*)&Vi[g + 4];
        }
        __syncthreads();

        // ---- logits for this thread's 4 keys
        const int kk0 = sub * 4;
        float sv[4] = {0.f, 0.f, 0.f, 0.f};
        #pragma unroll 2
        for (int d0 = 0; d0 < HDIM; d0 += 4) {
            float qr_[4], qi_[4];
            f4a(*(const float4*)&Qs_r[q][d0], qr_);
            f4a(*(const float4*)&Qs_i[q][d0], qi_);
            #pragma unroll
            for (int j = 0; j < 4; ++j) {
                float kr_[4], ki_[4];
                f4a(*(const float4*)&Ks_r[kk0 + j][d0], kr_);
                f4a(*(const float4*)&Ks_i[kk0 + j][d0], ki_);
                #pragma unroll
                for (int d = 0; d < 4; ++d) {
                    sv[j] = fmaf(qr_[d], kr_[d], sv[j]);
                    sv[j] = fmaf(qi_[d], ki_[d], sv[j]);
                }
            }
        }
        #pragma unroll
        for (int j = 0; j < 4; ++j) { sv[j] *= scale; Ss[q][kk0 + j] = sv[j]; }
        __syncthreads();

        // ---- online softmax bookkeeping (redundant across the 8 subs of a row)
        float m_tile = -1e30f;
        #pragma unroll
        for (int kk = 0; kk < KBT; ++kk) m_tile = fmaxf(m_tile, Ss[q][kk]);
        const float m_new = fmaxf(m_run, m_tile);
        const float fs = __expf(m_run - m_new);
        __syncthreads();                       // everyone done reading S
        #pragma unroll
        for (int j = 0; j < 4; ++j) Ss[q][kk0 + j] = __expf(sv[j] - m_new);
        __syncthreads();                       // P ready

        #pragma unroll
        for (int jj = 0; jj < 8; ++jj) { o_r[jj] *= fs; o_i[jj] *= fs; }
        float psum = 0.f;
        const int dc = sub * 8;
        for (int kk = 0; kk < KBT; ++kk) {
            const float p = Ss[q][kk];
            psum += p;
            float vr_[8], vi_[8];
            f4a(*(const float4*)&Vs_r[kk][dc],     vr_);
            f4a(*(const float4*)&Vs_r[kk][dc + 4], vr_ + 4);
            f4a(*(const float4*)&Vs_i[kk][dc],     vi_);
            f4a(*(const float4*)&Vs_i[kk][dc + 4], vi_ + 4);
            #pragma unroll
            for (int jj = 0; jj < 8; ++jj) {
                o_r[jj] = fmaf(p, vr_[jj], o_r[jj]);
                o_i[jj] = fmaf(p, vi_[jj], o_i[jj]);
            }
        }
        l_run = l_run * fs + psum;
        m_run = m_new;
    }

    const float inv = 1.0f / l_run;
    float wr[8], wi[8];
    #pragma unroll
    for (int jj = 0; jj < 8; ++jj) { wr[jj] = o_r[jj] * inv; wi[jj] = o_i[jj] * inv; }
    const size_t g = base + (size_t)(q0 + q) * DIM + sub * 8;
    *(float4*)&Qr[g]     = a4f(wr);
    *(float4*)&Qr[g + 4] = a4f(wr + 4);
    *(float4*)&Qi[g]     = a4f(wi);
    *(float4*)&Qi[g + 4] = a4f(wi + 4);
}

// ---------------------------------------------------------------- complex LayerNorm
//  x = cln(U + X) ; one wave per (b,s) row ; in-place on X (the residual/dest).
__global__ __launch_bounds__(256)
void cln_kernel(const float* __restrict__ Ur, const float* __restrict__ Ui,
                float* __restrict__ Xr, float* __restrict__ Xi,
                const float* __restrict__ Grr, const float* __restrict__ Gri,
                const float* __restrict__ Gii, const float* __restrict__ Bbr,
                const float* __restrict__ Bbi)
{
    const int lane = threadIdx.x & 63;
    const int row  = blockIdx.x * 4 + (threadIdx.x >> 6);
    const size_t off = (size_t)row * DIM;
    const int c0 = lane * 4;
    const int c1 = 256 + lane * 4;

    float xr[8], xi[8];
    {
        float a[4], b[4];
        f4a(*(const float4*)&Ur[off + c0], a); f4a(*(const float4*)&Xr[off + c0], b);
        #pragma unroll
        for (int j = 0; j < 4; ++j) xr[j] = a[j] + b[j];
        f4a(*(const float4*)&Ur[off + c1], a); f4a(*(const float4*)&Xr[off + c1], b);
        #pragma unroll
        for (int j = 0; j < 4; ++j) xr[4 + j] = a[j] + b[j];
        f4a(*(const float4*)&Ui[off + c0], a); f4a(*(const float4*)&Xi[off + c0], b);
        #pragma unroll
        for (int j = 0; j < 4; ++j) xi[j] = a[j] + b[j];
        f4a(*(const float4*)&Ui[off + c1], a); f4a(*(const float4*)&Xi[off + c1], b);
        #pragma unroll
        for (int j = 0; j < 4; ++j) xi[4 + j] = a[j] + b[j];
    }

    float sr = 0.f, si = 0.f, srr = 0.f, sii = 0.f, sri = 0.f;
    #pragma unroll
    for (int j = 0; j < 8; ++j) {
        sr += xr[j]; si += xi[j];
        srr = fmaf(xr[j], xr[j], srr);
        sii = fmaf(xi[j], xi[j], sii);
        sri = fmaf(xr[j], xi[j], sri);
    }
    #pragma unroll
    for (int m = 32; m >= 1; m >>= 1) {
        sr  += __shfl_xor(sr,  m, 64);
        si  += __shfl_xor(si,  m, 64);
        srr += __shfl_xor(srr, m, 64);
        sii += __shfl_xor(sii, m, 64);
        sri += __shfl_xor(sri, m, 64);
    }

    const float inv_d = 1.0f / DIM;
    const float mr = sr * inv_d, mi = si * inv_d;
    const float Vrr = srr * inv_d - mr * mr + 1e-5f;
    const float Vii = sii * inv_d - mi * mi + 1e-5f;
    const float Vri = sri * inv_d - mr * mi;
    const float s  = sqrtf(Vrr * Vii - Vri * Vri);
    const float tt = sqrtf(Vrr + Vii + 2.0f * s);
    const float ist = 1.0f / (s * tt);
    const float Wrr = (Vii + s) * ist;
    const float Wii = (Vrr + s) * ist;
    const float Wri = -Vri * ist;

    #pragma unroll
    for (int half = 0; half < 2; ++half) {
        const int c = half ? c1 : c0;
        float grr[4], gri[4], gii[4], pbr[4], pbi[4];
        f4a(*(const float4*)&Grr[c], grr);
        f4a(*(const float4*)&Gri[c], gri);
        f4a(*(const float4*)&Gii[c], gii);
        f4a(*(const float4*)&Bbr[c], pbr);
        f4a(*(const float4*)&Bbi[c], pbi);
        float outr[4], outi[4];
        #pragma unroll
        for (int j = 0; j < 4; ++j) {
            const int idx = half * 4 + j;
            const float cr = xr[idx] - mr;
            const float ci = xi[idx] - mi;
            const float hr = Wrr * cr + Wri * ci;
            const float hi = Wri * cr + Wii * ci;
            outr[j] = fmaf(grr[j], hr, fmaf(gri[j], hi, pbr[j]));
            outi[j] = fmaf(gri[j], hr, fmaf(gii[j], hi, pbi[j]));
        }
        *(float4*)&Xr[off + c] = a4f(outr);
        *(float4*)&Xi[off + c] = a4f(outi);
    }
}

// ---------------------------------------------------------------- host
extern "C" void kernel_launch(void* const* d_in, const int* in_sizes, int n_in,
                              void* d_out, int out_size, void* d_ws, size_t ws_size,
                              hipStream_t stream) {
    (void)in_sizes; (void)n_in; (void)out_size; (void)ws_size;

    const float* in_xr = (const float*)d_in[0];
    const float* in_xi = (const float*)d_in[1];
    const float* Wq_r = (const float*)d_in[2];
    const float* Wq_i = (const float*)d_in[3];
    const float* Wk_r = (const float*)d_in[4];
    const float* Wk_i = (const float*)d_in[5];
    const float* Wv_r = (const float*)d_in[6];
    const float* Wv_i = (const float*)d_in[7];
    const float* Wo_r = (const float*)d_in[8];
    const float* Wo_i = (const float*)d_in[9];
    const float* W1_r = (const float*)d_in[10];
    const float* W1_i = (const float*)d_in[11];
    const float* W2_r = (const float*)d_in[12];
    const float* W2_i = (const float*)d_in[13];
    const float* bq_r = (const float*)d_in[14];
    const float* bq_i = (const float*)d_in[15];
    const float* bk_r = (const float*)d_in[16];
    const float* bk_i = (const float*)d_in[17];
    const float* bv_r = (const float*)d_in[18];
    const float* bv_i = (const float*)d_in[19];
    const float* bo_r = (const float*)d_in[20];
    const float* bo_i = (const float*)d_in[21];
    const float* b1_r = (const float*)d_in[22];
    const float* b1_i = (const float*)d_in[23];
    const float* b2_r = (const float*)d_in[24];
    const float* b2_i = (const float*)d_in[25];
    const float* ln1_grr = (const float*)d_in[26];
    const float* ln1_gii = (const float*)d_in[27];
    const float* ln2_grr = (const float*)d_in[28];
    const float* ln2_gii = (const float*)d_in[29];
    const float* ln1_gri = (const float*)d_in[30];
    const float* ln1_br  = (const float*)d_in[31];
    const float* ln1_bi  = (const float*)d_in[32];
    const float* ln2_gri = (const float*)d_in[33];
    const float* ln2_br  = (const float*)d_in[34];
    const float* ln2_bi  = (const float*)d_in[35];

    float* outr = (float*)d_out;       // xr lives here
    float* outi = outr + BSD;          // xi lives here
    float* ws = (float*)d_ws;
    float* qr = ws + 0 * BSD; float* qi = ws + 1 * BSD;
    float* kr = ws + 2 * BSD; float* ki = ws + 3 * BSD;
    float* vr = ws + 4 * BSD; float* vi = ws + 5 * BSD;

    hipMemcpyAsync(outr, in_xr, BSD * sizeof(float), hipMemcpyDeviceToDevice, stream);
    hipMemcpyAsync(outi, in_xi, BSD * sizeof(float), hipMemcpyDeviceToDevice, stream);

    const dim3 ggrid(DIM / BN, ROWS / BM);   // (8, 128)
    const dim3 agrid(SEQ / QB, NH, NB);      // (32, 8, 8)
    const int  lgrid = ROWS / 4;             // 2048

    for (int l = 0; l < NL; ++l) {
        const size_t wo = (size_t)l * DIM * DIM;
        const size_t bo = (size_t)l * DIM;

        cgemm_kernel<false><<<ggrid, 256, 0, stream>>>(outr, outi, Wq_r + wo, Wq_i + wo,
                                                       bq_r + bo, bq_i + bo, qr, qi);
        cgemm_kernel<false><<<ggrid, 256, 0, stream>>>(outr, outi, Wk_r + wo, Wk_i + wo,
                                                       bk_r + bo, bk_i + bo, kr, ki);
        cgemm_kernel<false><<<ggrid, 256, 0, stream>>>(outr, outi, Wv_r + wo, Wv_i + wo,
                                                       bv_r + bo, bv_i + bo, vr, vi);
        attn_kernel<<<agrid, 256, 0, stream>>>(qr, qi, kr, ki, vr, vi);
        cgemm_kernel<false><<<ggrid, 256, 0, stream>>>(qr, qi, Wo_r + wo, Wo_i + wo,
                                                       bo_r + bo, bo_i + bo, kr, ki);
        cln_kernel<<<lgrid, 256, 0, stream>>>(kr, ki, outr, outi,
                                              ln1_grr + bo, ln1_gri + bo, ln1_gii + bo,
                                              ln1_br + bo, ln1_bi + bo);
        cgemm_kernel<true><<<ggrid, 256, 0, stream>>>(outr, outi, W1_r + wo, W1_i + wo,
                                                      b1_r + bo, b1_i + bo, vr, vi);
        cgemm_kernel<false><<<ggrid, 256, 0, stream>>>(vr, vi, W2_r + wo, W2_i + wo,
                                                       b2_r + bo, b2_i + bo, kr, ki);
        cln_kernel<<<lgrid, 256, 0, stream>>>(kr, ki, outr, outi,
                                              ln2_grr + bo, ln2_gri + bo, ln2_gii + bo,
                                              ln2_br + bo, ln2_bi + bo);
    }
}

// Round 2
// 7532.451 us; speedup vs baseline: 1.6991x; 1.6991x over previous
//
#include <hip/hip_runtime.h>
#include <cstddef>
#include <cstdint>

// ---------------------------------------------------------------- constants
constexpr int NB   = 8;
constexpr int SEQ  = 1024;
constexpr int DIM  = 512;
constexpr int NL   = 6;
constexpr int NH   = 8;
constexpr int HDIM = 64;
constexpr int ROWS = NB * SEQ;               // 8192
constexpr size_t BSD = (size_t)ROWS * DIM;   // 4,194,304

typedef __attribute__((ext_vector_type(8))) short bfrag;   // 8 bf16 = 16B (MFMA A/B frag)
typedef __attribute__((ext_vector_type(4))) float f32x4;   // MFMA C/D frag
typedef __attribute__((ext_vector_type(4))) unsigned short us4;

__device__ __forceinline__ void f4a(const float4 v, float* a) {
    a[0] = v.x; a[1] = v.y; a[2] = v.z; a[3] = v.w;
}
__device__ __forceinline__ float4 a4f(const float* a) {
    float4 v; v.x = a[0]; v.y = a[1]; v.z = a[2]; v.w = a[3]; return v;
}
__device__ __forceinline__ unsigned short f2bf(float f) {
    union { float f; uint32_t u; } x{f};
    return (unsigned short)((x.u + 0x7fffu + ((x.u >> 16) & 1u)) >> 16);
}

// ---------------------------------------------------------------- complex GEMM (fp32 vector)
//  MODE 0: fp32 outputs Yr/Yi.  MODE 1: bf16 Q̂/K̂ layout [bh][s][128].
//  MODE 2: bf16 V̂t layout [bh][128][s].
constexpr int BM = 64, BN = 64, BK = 16;

template <int MODE, bool RELU>
__global__ __launch_bounds__(256)
void cgemm_kernel(const float* __restrict__ Xr, const float* __restrict__ Xi,
                  const float* __restrict__ Wr, const float* __restrict__ Wi,
                  const float* __restrict__ Br, const float* __restrict__ Bi,
                  float* __restrict__ Yr, float* __restrict__ Yi,
                  unsigned short* __restrict__ Yh)
{
    constexpr int K = DIM, N = DIM;
    __shared__ __align__(16) float Xs_r[BK][BM + 4];
    __shared__ __align__(16) float Xs_i[BK][BM + 4];
    __shared__ __align__(16) float Ws_r[BK][BN + 4];
    __shared__ __align__(16) float Ws_i[BK][BN + 4];

    const int t  = threadIdx.x;
    const int tx = t & 15;
    const int ty = t >> 4;
    const int m0 = blockIdx.y * BM;
    const int n0 = blockIdx.x * BN;
    const int lr = t >> 2;
    const int lc = (t & 3) * 4;

    float accr[4][4] = {{0.f}}, acci[4][4] = {{0.f}};

    const float* gx_r = &Xr[(size_t)(m0 + lr) * K + lc];
    const float* gx_i = &Xi[(size_t)(m0 + lr) * K + lc];
    const float* gw_r = &Wr[(size_t)(n0 + lr) * K + lc];
    const float* gw_i = &Wi[(size_t)(n0 + lr) * K + lc];

    for (int k0 = 0; k0 < K; k0 += BK) {
        const float4 xr4 = *(const float4*)(gx_r + k0);
        const float4 xi4 = *(const float4*)(gx_i + k0);
        const float4 wr4 = *(const float4*)(gw_r + k0);
        const float4 wi4 = *(const float4*)(gw_i + k0);
        __syncthreads();
        Xs_r[lc+0][lr]=xr4.x; Xs_r[lc+1][lr]=xr4.y; Xs_r[lc+2][lr]=xr4.z; Xs_r[lc+3][lr]=xr4.w;
        Xs_i[lc+0][lr]=xi4.x; Xs_i[lc+1][lr]=xi4.y; Xs_i[lc+2][lr]=xi4.z; Xs_i[lc+3][lr]=xi4.w;
        Ws_r[lc+0][lr]=wr4.x; Ws_r[lc+1][lr]=wr4.y; Ws_r[lc+2][lr]=wr4.z; Ws_r[lc+3][lr]=wr4.w;
        Ws_i[lc+0][lr]=wi4.x; Ws_i[lc+1][lr]=wi4.y; Ws_i[lc+2][lr]=wi4.z; Ws_i[lc+3][lr]=wi4.w;
        __syncthreads();

        #pragma unroll
        for (int k = 0; k < BK; ++k) {
            float ar[4], ai[4], ur[4], ui[4];
            f4a(*(const float4*)&Xs_r[k][ty * 4], ar);
            f4a(*(const float4*)&Xs_i[k][ty * 4], ai);
            f4a(*(const float4*)&Ws_r[k][tx * 4], ur);
            f4a(*(const float4*)&Ws_i[k][tx * 4], ui);
            #pragma unroll
            for (int jm = 0; jm < 4; ++jm) {
                #pragma unroll
                for (int jn = 0; jn < 4; ++jn) {
                    accr[jm][jn] = fmaf(ar[jm], ur[jn], accr[jm][jn]);
                    accr[jm][jn] = fmaf(-ai[jm], ui[jn], accr[jm][jn]);
                    acci[jm][jn] = fmaf(ar[jm], ui[jn], acci[jm][jn]);
                    acci[jm][jn] = fmaf(ai[jm], ur[jn], acci[jm][jn]);
                }
            }
        }
    }

    float br_[4], bi_[4];
    f4a(*(const float4*)&Br[n0 + tx * 4], br_);
    f4a(*(const float4*)&Bi[n0 + tx * 4], bi_);

    if (MODE == 0) {
        #pragma unroll
        for (int jm = 0; jm < 4; ++jm) {
            float outr[4], outi[4];
            #pragma unroll
            for (int jn = 0; jn < 4; ++jn) {
                float vr = accr[jm][jn] + br_[jn];
                float vi = acci[jm][jn] + bi_[jn];
                if (RELU) { vr = fmaxf(vr, 0.f); vi = fmaxf(vi, 0.f); }
                outr[jn] = vr; outi[jn] = vi;
            }
            const size_t o = (size_t)(m0 + ty * 4 + jm) * N + n0 + tx * 4;
            *(float4*)&Yr[o] = a4f(outr);
            *(float4*)&Yi[o] = a4f(outi);
        }
    } else if (MODE == 1) {
        // Q̂/K̂: [bh][s][d̂=hd | hd+64], bf16
        const int b = m0 >> 10;
        const int h = n0 >> 6;
        const size_t rowbase = ((size_t)(b * NH + h) * SEQ + (m0 & 1023) + ty * 4) * 128 + tx * 4;
        #pragma unroll
        for (int jm = 0; jm < 4; ++jm) {
            us4 pr, pi;
            #pragma unroll
            for (int jn = 0; jn < 4; ++jn) {
                pr[jn] = f2bf(accr[jm][jn] + br_[jn]);
                pi[jn] = f2bf(acci[jm][jn] + bi_[jn]);
            }
            *(us4*)(Yh + rowbase + (size_t)jm * 128)      = pr;
            *(us4*)(Yh + rowbase + (size_t)jm * 128 + 64) = pi;
        }
    } else {
        // V̂t: [bh][d̂][s], bf16 (transposed write, 4 consecutive s packed)
        const int b = m0 >> 10;
        const int h = n0 >> 6;
        const int s0v = (m0 & 1023) + ty * 4;
        const size_t colbase = ((size_t)(b * NH + h) * 128 + tx * 4) * SEQ + s0v;
        #pragma unroll
        for (int jn = 0; jn < 4; ++jn) {
            us4 pr, pi;
            #pragma unroll
            for (int jm = 0; jm < 4; ++jm) {
                pr[jm] = f2bf(accr[jm][jn] + br_[jn]);
                pi[jm] = f2bf(acci[jm][jn] + bi_[jn]);
            }
            *(us4*)(Yh + colbase + (size_t)jn * SEQ)              = pr;
            *(us4*)(Yh + colbase + (size_t)(64 + jn) * SEQ)       = pi;
        }
    }
}

// ---------------------------------------------------------------- MFMA flash attention
//  Real flash-attn with D̂=128 (concat r|i). Block = 4 waves x 16 queries, KV tile 64.
//  S-mfma: A=Q̂ rows (regs), B=K̂ rows (LDS, XOR-swizzled). PV: Oᵀ = V̂ᵀ·Pᵀ.
__global__ __launch_bounds__(256)
void attn_mfma(const unsigned short* __restrict__ Qh,
               const unsigned short* __restrict__ Kh,
               const unsigned short* __restrict__ Vth,
               float* __restrict__ Or, float* __restrict__ Oi)
{
    __shared__ __align__(16) char smem[41216];
    char* Ksm = smem;            // [64 key][128 d̂] bf16, swizzled, 16KB
    char* Vsm = smem + 16384;    // [128 d̂][64 key] bf16, swizzled, 16KB
    const int t    = threadIdx.x;
    const int lane = t & 63;
    const int wv   = t >> 6;
    const int c    = lane & 15;   // fragment column
    const int g    = lane >> 4;   // fragment group
    char* Pw = smem + 32768 + wv * 2048;   // per-wave P [16 q][64 key] bf16, swizzled

    const int q0 = blockIdx.x * 64;
    const int hh = blockIdx.y, bb = blockIdx.z;
    const int bh = bb * NH + hh;
    const size_t qkb = (size_t)bh * SEQ * 128;
    const size_t vtb = (size_t)bh * 128 * SEQ;

    // Q A-fragments held in registers (4 k-steps of 32)
    bfrag qf[4];
    {
        const unsigned short* qp = Qh + qkb + (size_t)(q0 + wv * 16 + c) * 128 + g * 8;
        #pragma unroll
        for (int ks = 0; ks < 4; ++ks) qf[ks] = *(const bfrag*)(qp + ks * 32);
    }

    f32x4 oacc[8];
    #pragma unroll
    for (int i = 0; i < 8; ++i) oacc[i] = (f32x4){0.f, 0.f, 0.f, 0.f};
    float mrun[4], lrun[4];
    #pragma unroll
    for (int r = 0; r < 4; ++r) { mrun[r] = -1e30f; lrun[r] = 0.f; }

    const int kkey = t >> 2, kq = t & 3;   // K stage mapping
    const unsigned short* kgp = Kh + qkb + (size_t)kkey * 128 + kq * 32;
    const int vd = t >> 1, vh2 = t & 1;    // V stage mapping
    const unsigned short* vgp = Vth + vtb + (size_t)vd * SEQ + vh2 * 32;

    for (int k0 = 0; k0 < SEQ; k0 += 64) {
        bfrag krg[4], vrg[4];
        #pragma unroll
        for (int j = 0; j < 4; ++j) krg[j] = *(const bfrag*)(kgp + (size_t)k0 * 128 + j * 8);
        #pragma unroll
        for (int j = 0; j < 4; ++j) vrg[j] = *(const bfrag*)(vgp + k0 + j * 8);
        __syncthreads();
        #pragma unroll
        for (int j = 0; j < 4; ++j) {
            const int boff = (kkey * 256 + (kq * 32 + j * 8) * 2) ^ ((kkey & 7) << 4);
            *(bfrag*)(Ksm + boff) = krg[j];
        }
        #pragma unroll
        for (int j = 0; j < 4; ++j) {
            const int boff = (vd * 128 + (vh2 * 32 + j * 8) * 2) ^ ((vd & 7) << 4);
            *(bfrag*)(Vsm + boff) = vrg[j];
        }
        __syncthreads();

        // ---- S = Q̂ · K̂ᵀ  (per wave: 16 q x 64 key)
        f32x4 sa[4];
        #pragma unroll
        for (int nt = 0; nt < 4; ++nt) sa[nt] = (f32x4){0.f, 0.f, 0.f, 0.f};
        #pragma unroll
        for (int nt = 0; nt < 4; ++nt) {
            const int key = nt * 16 + c;
            #pragma unroll
            for (int ks = 0; ks < 4; ++ks) {
                const int boff = (key * 256 + (ks * 32 + g * 8) * 2) ^ ((key & 7) << 4);
                const bfrag bk = *(const bfrag*)(Ksm + boff);
                sa[nt] = __builtin_amdgcn_mfma_f32_16x16x32_bf16(qf[ks], bk, sa[nt], 0, 0, 0);
            }
        }

        // ---- online softmax (rows live across the 16-lane column groups)
        float sv[4][4];
        #pragma unroll
        for (int nt = 0; nt < 4; ++nt)
            #pragma unroll
            for (int r = 0; r < 4; ++r) sv[nt][r] = sa[nt][r] * 0.125f;

        float mt[4], fs[4], ps[4], mn[4];
        #pragma unroll
        for (int r = 0; r < 4; ++r)
            mt[r] = fmaxf(fmaxf(sv[0][r], sv[1][r]), fmaxf(sv[2][r], sv[3][r]));
        #pragma unroll
        for (int m = 1; m <= 8; m <<= 1) {
            #pragma unroll
            for (int r = 0; r < 4; ++r) mt[r] = fmaxf(mt[r], __shfl_xor(mt[r], m, 64));
        }
        #pragma unroll
        for (int r = 0; r < 4; ++r) {
            mn[r] = fmaxf(mrun[r], mt[r]);
            fs[r] = __expf(mrun[r] - mn[r]);
            ps[r] = 0.f;
        }
        #pragma unroll
        for (int nt = 0; nt < 4; ++nt) {
            const int col2 = (nt * 16 + c) * 2;
            #pragma unroll
            for (int r = 0; r < 4; ++r) {
                const float p = __expf(sv[nt][r] - mn[r]);
                ps[r] += p;
                const int qrow = 4 * g + r;
                *(unsigned short*)(Pw + ((qrow * 128 + col2) ^ ((qrow & 7) << 4))) = f2bf(p);
            }
        }
        #pragma unroll
        for (int m = 1; m <= 8; m <<= 1) {
            #pragma unroll
            for (int r = 0; r < 4; ++r) ps[r] += __shfl_xor(ps[r], m, 64);
        }
        #pragma unroll
        for (int r = 0; r < 4; ++r) {
            lrun[r] = lrun[r] * fs[r] + ps[r];
            mrun[r] = mn[r];
        }

        // redistribute rescale factor to this lane's O column (q = c)
        {
            const int rr = c & 3;
            float vsel = fs[0];
            vsel = (rr == 1) ? fs[1] : vsel;
            vsel = (rr == 2) ? fs[2] : vsel;
            vsel = (rr == 3) ? fs[3] : vsel;
            const float fsc = __shfl(vsel, ((c >> 2) << 4) | (c & 3), 64);
            #pragma unroll
            for (int i = 0; i < 8; ++i) {
                oacc[i][0] *= fsc; oacc[i][1] *= fsc; oacc[i][2] *= fsc; oacc[i][3] *= fsc;
            }
        }

        asm volatile("s_waitcnt lgkmcnt(0)" ::: "memory");   // P writes visible (wave-local)
        __builtin_amdgcn_sched_barrier(0);

        // ---- Oᵀ += V̂ᵀ · Pᵀ   (per wave: 128 d̂ x 16 q)
        #pragma unroll
        for (int k2 = 0; k2 < 2; ++k2) {
            const int kb2 = (k2 * 32 + g * 8) * 2;
            const bfrag pb = *(const bfrag*)(Pw + ((c * 128 + kb2) ^ ((c & 7) << 4)));
            #pragma unroll
            for (int mtl = 0; mtl < 8; ++mtl) {
                const int d = mtl * 16 + c;
                const bfrag va = *(const bfrag*)(Vsm + ((d * 128 + kb2) ^ ((d & 7) << 4)));
                oacc[mtl] = __builtin_amdgcn_mfma_f32_16x16x32_bf16(va, pb, oacc[mtl], 0, 0, 0);
            }
        }
    }

    // ---- normalize + transpose via LDS + coalesced store
    {
        const int rr = c & 3;
        float inv[4];
        #pragma unroll
        for (int r = 0; r < 4; ++r) inv[r] = 1.f / lrun[r];
        float vsel = inv[0];
        vsel = (rr == 1) ? inv[1] : vsel;
        vsel = (rr == 2) ? inv[2] : vsel;
        vsel = (rr == 3) ? inv[3] : vsel;
        const float ic = __shfl(vsel, ((c >> 2) << 4) | (c & 3), 64);
        #pragma unroll
        for (int i = 0; i < 8; ++i) {
            oacc[i][0] *= ic; oacc[i][1] *= ic; oacc[i][2] *= ic; oacc[i][3] *= ic;
        }
    }
    __syncthreads();   // done with K/V LDS; reuse as transpose scratch
    float* Ox = (float*)(smem + wv * 8192);   // [128 d̂][16 q]
    #pragma unroll
    for (int mtl = 0; mtl < 8; ++mtl)
        #pragma unroll
        for (int r = 0; r < 4; ++r)
            Ox[(mtl * 16 + 4 * g + r) * 16 + c] = oacc[mtl][r];
    asm volatile("s_waitcnt lgkmcnt(0)" ::: "memory");
    __builtin_amdgcn_sched_barrier(0);

    const int q = lane >> 2, qt = lane & 3;
    float* dst = (qt >> 1) ? Oi : Or;
    const size_t orow = ((size_t)bb * SEQ + q0 + wv * 16 + q) * DIM + hh * 64 + (qt & 1) * 32;
    #pragma unroll
    for (int j = 0; j < 8; ++j) {
        float tmp[4];
        #pragma unroll
        for (int e = 0; e < 4; ++e) tmp[e] = Ox[(qt * 32 + j * 4 + e) * 16 + q];
        *(float4*)&dst[orow + j * 4] = a4f(tmp);
    }
}

// ---------------------------------------------------------------- complex LayerNorm
__global__ __launch_bounds__(256)
void cln_kernel(const float* __restrict__ Ur, const float* __restrict__ Ui,
                float* __restrict__ Xr, float* __restrict__ Xi,
                const float* __restrict__ Grr, const float* __restrict__ Gri,
                const float* __restrict__ Gii, const float* __restrict__ Bbr,
                const float* __restrict__ Bbi)
{
    const int lane = threadIdx.x & 63;
    const int row  = blockIdx.x * 4 + (threadIdx.x >> 6);
    const size_t off = (size_t)row * DIM;
    const int c0 = lane * 4;
    const int c1 = 256 + lane * 4;

    float xr[8], xi[8];
    {
        float a[4], b[4];
        f4a(*(const float4*)&Ur[off + c0], a); f4a(*(const float4*)&Xr[off + c0], b);
        #pragma unroll
        for (int j = 0; j < 4; ++j) xr[j] = a[j] + b[j];
        f4a(*(const float4*)&Ur[off + c1], a); f4a(*(const float4*)&Xr[off + c1], b);
        #pragma unroll
        for (int j = 0; j < 4; ++j) xr[4 + j] = a[j] + b[j];
        f4a(*(const float4*)&Ui[off + c0], a); f4a(*(const float4*)&Xi[off + c0], b);
        #pragma unroll
        for (int j = 0; j < 4; ++j) xi[j] = a[j] + b[j];
        f4a(*(const float4*)&Ui[off + c1], a); f4a(*(const float4*)&Xi[off + c1], b);
        #pragma unroll
        for (int j = 0; j < 4; ++j) xi[4 + j] = a[j] + b[j];
    }

    float sr = 0.f, si = 0.f, srr = 0.f, sii = 0.f, sri = 0.f;
    #pragma unroll
    for (int j = 0; j < 8; ++j) {
        sr += xr[j]; si += xi[j];
        srr = fmaf(xr[j], xr[j], srr);
        sii = fmaf(xi[j], xi[j], sii);
        sri = fmaf(xr[j], xi[j], sri);
    }
    #pragma unroll
    for (int m = 32; m >= 1; m >>= 1) {
        sr  += __shfl_xor(sr,  m, 64);
        si  += __shfl_xor(si,  m, 64);
        srr += __shfl_xor(srr, m, 64);
        sii += __shfl_xor(sii, m, 64);
        sri += __shfl_xor(sri, m, 64);
    }

    const float inv_d = 1.0f / DIM;
    const float mr = sr * inv_d, mi = si * inv_d;
    const float Vrr = srr * inv_d - mr * mr + 1e-5f;
    const float Vii = sii * inv_d - mi * mi + 1e-5f;
    const float Vri = sri * inv_d - mr * mi;
    const float s  = sqrtf(Vrr * Vii - Vri * Vri);
    const float tt = sqrtf(Vrr + Vii + 2.0f * s);
    const float ist = 1.0f / (s * tt);
    const float Wrr = (Vii + s) * ist;
    const float Wii = (Vrr + s) * ist;
    const float Wri = -Vri * ist;

    #pragma unroll
    for (int half = 0; half < 2; ++half) {
        const int c = half ? c1 : c0;
        float grr[4], gri[4], gii[4], pbr[4], pbi[4];
        f4a(*(const float4*)&Grr[c], grr);
        f4a(*(const float4*)&Gri[c], gri);
        f4a(*(const float4*)&Gii[c], gii);
        f4a(*(const float4*)&Bbr[c], pbr);
        f4a(*(const float4*)&Bbi[c], pbi);
        float outr[4], outi[4];
        #pragma unroll
        for (int j = 0; j < 4; ++j) {
            const int idx = half * 4 + j;
            const float cr = xr[idx] - mr;
            const float ci = xi[idx] - mi;
            const float hr = Wrr * cr + Wri * ci;
            const float hi = Wri * cr + Wii * ci;
            outr[j] = fmaf(grr[j], hr, fmaf(gri[j], hi, pbr[j]));
            outi[j] = fmaf(gri[j], hr, fmaf(gii[j], hi, pbi[j]));
        }
        *(float4*)&Xr[off + c] = a4f(outr);
        *(float4*)&Xi[off + c] = a4f(outi);
    }
}

// ---------------------------------------------------------------- host
extern "C" void kernel_launch(void* const* d_in, const int* in_sizes, int n_in,
                              void* d_out, int out_size, void* d_ws, size_t ws_size,
                              hipStream_t stream) {
    (void)in_sizes; (void)n_in; (void)out_size; (void)ws_size;

    const float* in_xr = (const float*)d_in[0];
    const float* in_xi = (const float*)d_in[1];
    const float* Wq_r = (const float*)d_in[2];
    const float* Wq_i = (const float*)d_in[3];
    const float* Wk_r = (const float*)d_in[4];
    const float* Wk_i = (const float*)d_in[5];
    const float* Wv_r = (const float*)d_in[6];
    const float* Wv_i = (const float*)d_in[7];
    const float* Wo_r = (const float*)d_in[8];
    const float* Wo_i = (const float*)d_in[9];
    const float* W1_r = (const float*)d_in[10];
    const float* W1_i = (const float*)d_in[11];
    const float* W2_r = (const float*)d_in[12];
    const float* W2_i = (const float*)d_in[13];
    const float* bq_r = (const float*)d_in[14];
    const float* bq_i = (const float*)d_in[15];
    const float* bk_r = (const float*)d_in[16];
    const float* bk_i = (const float*)d_in[17];
    const float* bv_r = (const float*)d_in[18];
    const float* bv_i = (const float*)d_in[19];
    const float* bo_r = (const float*)d_in[20];
    const float* bo_i = (const float*)d_in[21];
    const float* b1_r = (const float*)d_in[22];
    const float* b1_i = (const float*)d_in[23];
    const float* b2_r = (const float*)d_in[24];
    const float* b2_i = (const float*)d_in[25];
    const float* ln1_grr = (const float*)d_in[26];
    const float* ln1_gii = (const float*)d_in[27];
    const float* ln2_grr = (const float*)d_in[28];
    const float* ln2_gii = (const float*)d_in[29];
    const float* ln1_gri = (const float*)d_in[30];
    const float* ln1_br  = (const float*)d_in[31];
    const float* ln1_bi  = (const float*)d_in[32];
    const float* ln2_gri = (const float*)d_in[33];
    const float* ln2_br  = (const float*)d_in[34];
    const float* ln2_bi  = (const float*)d_in[35];

    float* outr = (float*)d_out;
    float* outi = outr + BSD;
    float* ws = (float*)d_ws;
    // workspace carve (83.9 MB total):
    float* Ar = ws;                         // attn-out r / FFN hidden r
    float* Ai = ws + BSD;                   // attn-out i / FFN hidden i
    unsigned short* Qh  = (unsigned short*)(ws + 2 * BSD);  // 2*BSD bf16 each
    unsigned short* Kh  = Qh + 2 * BSD;
    unsigned short* Vth = Kh + 2 * BSD;
    float* Pr = (float*)Qh;                 // O-proj / FFN2 out r (reuses Q̂ space)
    float* Pi = (float*)Kh;                 // O-proj / FFN2 out i (reuses K̂ space)

    hipMemcpyAsync(outr, in_xr, BSD * sizeof(float), hipMemcpyDeviceToDevice, stream);
    hipMemcpyAsync(outi, in_xi, BSD * sizeof(float), hipMemcpyDeviceToDevice, stream);

    const dim3 ggrid(DIM / BN, ROWS / BM);   // (8, 128)
    const dim3 agrid(SEQ / 64, NH, NB);      // (16, 8, 8)
    const int  lgrid = ROWS / 4;             // 2048

    for (int l = 0; l < NL; ++l) {
        const size_t wo = (size_t)l * DIM * DIM;
        const size_t bo = (size_t)l * DIM;

        cgemm_kernel<1, false><<<ggrid, 256, 0, stream>>>(outr, outi, Wq_r + wo, Wq_i + wo,
                                                          bq_r + bo, bq_i + bo, nullptr, nullptr, Qh);
        cgemm_kernel<1, false><<<ggrid, 256, 0, stream>>>(outr, outi, Wk_r + wo, Wk_i + wo,
                                                          bk_r + bo, bk_i + bo, nullptr, nullptr, Kh);
        cgemm_kernel<2, false><<<ggrid, 256, 0, stream>>>(outr, outi, Wv_r + wo, Wv_i + wo,
                                                          bv_r + bo, bv_i + bo, nullptr, nullptr, Vth);
        attn_mfma<<<agrid, 256, 0, stream>>>(Qh, Kh, Vth, Ar, Ai);
        cgemm_kernel<0, false><<<ggrid, 256, 0, stream>>>(Ar, Ai, Wo_r + wo, Wo_i + wo,
                                                          bo_r + bo, bo_i + bo, Pr, Pi, nullptr);
        cln_kernel<<<lgrid, 256, 0, stream>>>(Pr, Pi, outr, outi,
                                              ln1_grr + bo, ln1_gri + bo, ln1_gii + bo,
                                              ln1_br + bo, ln1_bi + bo);
        cgemm_kernel<0, true><<<ggrid, 256, 0, stream>>>(outr, outi, W1_r + wo, W1_i + wo,
                                                         b1_r + bo, b1_i + bo, Ar, Ai, nullptr);
        cgemm_kernel<0, false><<<ggrid, 256, 0, stream>>>(Ar, Ai, W2_r + wo, W2_i + wo,
                                                          b2_r + bo, b2_i + bo, Pr, Pi, nullptr);
        cln_kernel<<<lgrid, 256, 0, stream>>>(Pr, Pi, outr, outi,
                                              ln2_grr + bo, ln2_gri + bo, ln2_gii + bo,
                                              ln2_br + bo, ln2_bi + bo);
    }
}

// Round 3
// 1840.162 us; speedup vs baseline: 6.9549x; 4.0934x over previous
//
#include <hip/hip_runtime.h>
#include <cstddef>
#include <cstdint>

// ---------------------------------------------------------------- constants
constexpr int NB   = 8;
constexpr int SEQ  = 1024;
constexpr int DIM  = 512;
constexpr int NL   = 6;
constexpr int NH   = 8;
constexpr int HDIM = 64;
constexpr int ROWS = NB * SEQ;               // 8192
constexpr size_t BSD = (size_t)ROWS * DIM;   // 4,194,304
constexpr int KHAT = 1024;                   // concat K dim

typedef __attribute__((ext_vector_type(8))) short bfrag;   // 8 bf16 = 16B
typedef __attribute__((ext_vector_type(4))) float f32x4;
typedef __attribute__((ext_vector_type(4))) unsigned short us4;

__device__ __forceinline__ void f4a(const float4 v, float* a) {
    a[0] = v.x; a[1] = v.y; a[2] = v.z; a[3] = v.w;
}
__device__ __forceinline__ float4 a4f(const float* a) {
    float4 v; v.x = a[0]; v.y = a[1]; v.z = a[2]; v.w = a[3]; return v;
}
__device__ __forceinline__ unsigned short f2bf(float f) {
    union { float f; uint32_t u; } x{f};
    return (unsigned short)((x.u + 0x7fffu + ((x.u >> 16) & 1u)) >> 16);
}

// ---------------------------------------------------------------- weight prep
//  Build B̂ [1024 ň][1024 k̂] bf16 and composed bias [1024] per linear.
//  lin 0..2 (q,k,v): ň = h*128 + d̂ (d̂<64 -> real out, else imag out)
//  lin 3..5 (o,f1,f2): ň<512 -> real out, else imag.
//  k̂<512: real? Wr : Wi ; k̂>=512: real? -Wi : Wr.
struct PrepArgs {
    const float* Wr[6]; const float* Wi[6];
    const float* br[6]; const float* bi[6];
};

__global__ __launch_bounds__(256)
void prep_kernel(PrepArgs a, unsigned short* __restrict__ Ball,
                 float* __restrict__ biasall, int layer)
{
    const int lin = blockIdx.y;
    const int nh_ = blockIdx.x;           // ň
    const float* Wr = a.Wr[lin] + (size_t)layer * DIM * DIM;
    const float* Wi = a.Wi[lin] + (size_t)layer * DIM * DIM;

    bool real; int n0;
    if (lin < 3) { const int dh = nh_ & 127; real = dh < 64; n0 = (nh_ >> 7) * 64 + (dh & 63); }
    else         { real = nh_ < 512; n0 = nh_ & 511; }

    const int t = threadIdx.x;
    const int kk = (t * 4) & 511;
    const bool fh = t < 128;
    const float* src;
    float sgn = 1.f;
    if (fh) src = real ? Wr : Wi;
    else { if (real) { src = Wi; sgn = -1.f; } else src = Wr; }

    float v[4];
    f4a(*(const float4*)(src + (size_t)n0 * 512 + kk), v);
    us4 o;
    #pragma unroll
    for (int j = 0; j < 4; ++j) o[j] = f2bf(sgn * v[j]);
    *(us4*)(Ball + (size_t)lin * KHAT * KHAT + (size_t)nh_ * KHAT + t * 4) = o;
    if (t == 0)
        biasall[lin * KHAT + nh_] = real ? a.br[lin][layer * DIM + n0]
                                         : a.bi[lin][layer * DIM + n0];
}

// ---------------------------------------------------------------- MFMA GEMM
//  Y[m][n] = Σ_k X̂[m][k] B̂[n][k] + bias[n];  M=8192, N=K=1024.
//  128x128 tile, BK=32, 4 waves (2x2), each wave 4x4 16x16x32 frags.
//  EPI 0: bf16 Q̂/K̂ [bh][s][128]   EPI 1: bf16 V̂t [bh][128][s]
//  EPI 2: fp32 Yr/Yi split          EPI 3: CReLU bf16 [m][1024]
template <int EPI>
__global__ __launch_bounds__(256)
void gemm_mfma(const unsigned short* __restrict__ Xh,
               const unsigned short* __restrict__ Bh,
               const float* __restrict__ bias,
               unsigned short* __restrict__ Yh,
               float* __restrict__ Yr, float* __restrict__ Yi)
{
    __shared__ __align__(16) unsigned short Asm[128 * 32];
    __shared__ __align__(16) unsigned short Bsm[128 * 32];

    const int t = threadIdx.x, lane = t & 63, w = t >> 6;
    const int wm = w >> 1, wn = w & 1;
    const int c = lane & 15, g = lane >> 4;
    const int m0 = blockIdx.y * 128, n0 = blockIdx.x * 128;

    f32x4 acc[4][4];
    #pragma unroll
    for (int i = 0; i < 4; ++i)
        #pragma unroll
        for (int j = 0; j < 4; ++j) acc[i][j] = (f32x4){0.f, 0.f, 0.f, 0.f};

    const int tr = t >> 2;            // 0..63 staging row
    const int tc = (t & 3) * 8;       // ushort col offset
    const unsigned short* gA = Xh + (size_t)(m0 + tr) * KHAT + tc;
    const unsigned short* gB = Bh + (size_t)(n0 + tr) * KHAT + tc;

    bfrag sA0 = *(const bfrag*)(gA);
    bfrag sA1 = *(const bfrag*)(gA + 64 * KHAT);
    bfrag sB0 = *(const bfrag*)(gB);
    bfrag sB1 = *(const bfrag*)(gB + 64 * KHAT);

    for (int ks = 0; ks < 32; ++ks) {
        __syncthreads();
        *(bfrag*)(Asm + tr * 32 + tc)        = sA0;
        *(bfrag*)(Asm + (64 + tr) * 32 + tc) = sA1;
        *(bfrag*)(Bsm + tr * 32 + tc)        = sB0;
        *(bfrag*)(Bsm + (64 + tr) * 32 + tc) = sB1;
        if (ks < 31) {
            const int k0 = (ks + 1) * 32;
            sA0 = *(const bfrag*)(gA + k0);
            sA1 = *(const bfrag*)(gA + 64 * KHAT + k0);
            sB0 = *(const bfrag*)(gB + k0);
            sB1 = *(const bfrag*)(gB + 64 * KHAT + k0);
        }
        __syncthreads();

        bfrag af[4], bf2[4];
        #pragma unroll
        for (int mi = 0; mi < 4; ++mi)
            af[mi] = *(const bfrag*)(Asm + (wm * 64 + mi * 16 + c) * 32 + g * 8);
        #pragma unroll
        for (int ni = 0; ni < 4; ++ni)
            bf2[ni] = *(const bfrag*)(Bsm + (wn * 64 + ni * 16 + c) * 32 + g * 8);
        #pragma unroll
        for (int mi = 0; mi < 4; ++mi)
            #pragma unroll
            for (int ni = 0; ni < 4; ++ni)
                acc[mi][ni] = __builtin_amdgcn_mfma_f32_16x16x32_bf16(
                    af[mi], bf2[ni], acc[mi][ni], 0, 0, 0);
    }

    // ---- epilogue
    const int mbase = m0 + wm * 64;
    const int nbase = n0 + wn * 64;
    #pragma unroll
    for (int mi = 0; mi < 4; ++mi) {
        #pragma unroll
        for (int ni = 0; ni < 4; ++ni) {
            const int n = nbase + ni * 16 + c;
            const float bv = bias[n];
            float v[4];
            #pragma unroll
            for (int r = 0; r < 4; ++r) v[r] = acc[mi][ni][r] + bv;
            const int mrow = mbase + mi * 16 + g * 4;
            if (EPI == 0) {
                const int b = mrow >> 10, s = mrow & 1023;
                const int h = n >> 7, dh = n & 127;
                const size_t a = ((size_t)(b * NH + h) * SEQ + s) * 128 + dh;
                #pragma unroll
                for (int r = 0; r < 4; ++r) Yh[a + (size_t)r * 128] = f2bf(v[r]);
            } else if (EPI == 1) {
                const int b = mrow >> 10, s = mrow & 1023;
                const int h = n >> 7, dh = n & 127;
                const size_t a = ((size_t)(b * NH + h) * 128 + dh) * SEQ + s;
                us4 o;
                #pragma unroll
                for (int r = 0; r < 4; ++r) o[r] = f2bf(v[r]);
                *(us4*)(Yh + a) = o;
            } else if (EPI == 2) {
                float* dst = (n < 512) ? Yr : Yi;
                const int nn = n & 511;
                #pragma unroll
                for (int r = 0; r < 4; ++r) dst[(size_t)(mrow + r) * DIM + nn] = v[r];
            } else {
                #pragma unroll
                for (int r = 0; r < 4; ++r)
                    Yh[(size_t)(mrow + r) * KHAT + n] = f2bf(fmaxf(v[r], 0.f));
            }
        }
    }
}

// ---------------------------------------------------------------- MFMA flash attention
__global__ __launch_bounds__(256)
void attn_mfma(const unsigned short* __restrict__ Qh,
               const unsigned short* __restrict__ Kh,
               const unsigned short* __restrict__ Vth,
               unsigned short* __restrict__ Ah)
{
    __shared__ __align__(16) char smem[41216];
    char* Ksm = smem;
    char* Vsm = smem + 16384;
    const int t    = threadIdx.x;
    const int lane = t & 63;
    const int wv   = t >> 6;
    const int c    = lane & 15;
    const int g    = lane >> 4;
    char* Pw = smem + 32768 + wv * 2048;

    const int q0 = blockIdx.x * 64;
    const int hh = blockIdx.y, bb = blockIdx.z;
    const int bh = bb * NH + hh;
    const size_t qkb = (size_t)bh * SEQ * 128;
    const size_t vtb = (size_t)bh * 128 * SEQ;

    bfrag qf[4];
    {
        const unsigned short* qp = Qh + qkb + (size_t)(q0 + wv * 16 + c) * 128 + g * 8;
        #pragma unroll
        for (int ks = 0; ks < 4; ++ks) qf[ks] = *(const bfrag*)(qp + ks * 32);
    }

    f32x4 oacc[8];
    #pragma unroll
    for (int i = 0; i < 8; ++i) oacc[i] = (f32x4){0.f, 0.f, 0.f, 0.f};
    float mrun[4], lrun[4];
    #pragma unroll
    for (int r = 0; r < 4; ++r) { mrun[r] = -1e30f; lrun[r] = 0.f; }

    const int kkey = t >> 2, kq = t & 3;
    const unsigned short* kgp = Kh + qkb + (size_t)kkey * 128 + kq * 32;
    const int vd = t >> 1, vh2 = t & 1;
    const unsigned short* vgp = Vth + vtb + (size_t)vd * SEQ + vh2 * 32;

    for (int k0 = 0; k0 < SEQ; k0 += 64) {
        bfrag krg[4], vrg[4];
        #pragma unroll
        for (int j = 0; j < 4; ++j) krg[j] = *(const bfrag*)(kgp + (size_t)k0 * 128 + j * 8);
        #pragma unroll
        for (int j = 0; j < 4; ++j) vrg[j] = *(const bfrag*)(vgp + k0 + j * 8);
        __syncthreads();
        #pragma unroll
        for (int j = 0; j < 4; ++j) {
            const int boff = (kkey * 256 + (kq * 32 + j * 8) * 2) ^ ((kkey & 7) << 4);
            *(bfrag*)(Ksm + boff) = krg[j];
        }
        #pragma unroll
        for (int j = 0; j < 4; ++j) {
            const int boff = (vd * 128 + (vh2 * 32 + j * 8) * 2) ^ ((vd & 7) << 4);
            *(bfrag*)(Vsm + boff) = vrg[j];
        }
        __syncthreads();

        f32x4 sa[4];
        #pragma unroll
        for (int nt = 0; nt < 4; ++nt) sa[nt] = (f32x4){0.f, 0.f, 0.f, 0.f};
        #pragma unroll
        for (int nt = 0; nt < 4; ++nt) {
            const int key = nt * 16 + c;
            #pragma unroll
            for (int ks = 0; ks < 4; ++ks) {
                const int boff = (key * 256 + (ks * 32 + g * 8) * 2) ^ ((key & 7) << 4);
                const bfrag bk = *(const bfrag*)(Ksm + boff);
                sa[nt] = __builtin_amdgcn_mfma_f32_16x16x32_bf16(qf[ks], bk, sa[nt], 0, 0, 0);
            }
        }

        float sv[4][4];
        #pragma unroll
        for (int nt = 0; nt < 4; ++nt)
            #pragma unroll
            for (int r = 0; r < 4; ++r) sv[nt][r] = sa[nt][r] * 0.125f;

        float mt[4], fs[4], ps[4], mn[4];
        #pragma unroll
        for (int r = 0; r < 4; ++r)
            mt[r] = fmaxf(fmaxf(sv[0][r], sv[1][r]), fmaxf(sv[2][r], sv[3][r]));
        #pragma unroll
        for (int m = 1; m <= 8; m <<= 1) {
            #pragma unroll
            for (int r = 0; r < 4; ++r) mt[r] = fmaxf(mt[r], __shfl_xor(mt[r], m, 64));
        }
        #pragma unroll
        for (int r = 0; r < 4; ++r) {
            mn[r] = fmaxf(mrun[r], mt[r]);
            fs[r] = __expf(mrun[r] - mn[r]);
            ps[r] = 0.f;
        }
        #pragma unroll
        for (int nt = 0; nt < 4; ++nt) {
            const int col2 = (nt * 16 + c) * 2;
            #pragma unroll
            for (int r = 0; r < 4; ++r) {
                const float p = __expf(sv[nt][r] - mn[r]);
                ps[r] += p;
                const int qrow = 4 * g + r;
                *(unsigned short*)(Pw + ((qrow * 128 + col2) ^ ((qrow & 7) << 4))) = f2bf(p);
            }
        }
        #pragma unroll
        for (int m = 1; m <= 8; m <<= 1) {
            #pragma unroll
            for (int r = 0; r < 4; ++r) ps[r] += __shfl_xor(ps[r], m, 64);
        }
        #pragma unroll
        for (int r = 0; r < 4; ++r) {
            lrun[r] = lrun[r] * fs[r] + ps[r];
            mrun[r] = mn[r];
        }

        {
            const int rr = c & 3;
            float vsel = fs[0];
            vsel = (rr == 1) ? fs[1] : vsel;
            vsel = (rr == 2) ? fs[2] : vsel;
            vsel = (rr == 3) ? fs[3] : vsel;
            const float fsc = __shfl(vsel, ((c >> 2) << 4) | (c & 3), 64);
            #pragma unroll
            for (int i = 0; i < 8; ++i) {
                oacc[i][0] *= fsc; oacc[i][1] *= fsc; oacc[i][2] *= fsc; oacc[i][3] *= fsc;
            }
        }

        asm volatile("s_waitcnt lgkmcnt(0)" ::: "memory");
        __builtin_amdgcn_sched_barrier(0);

        #pragma unroll
        for (int k2 = 0; k2 < 2; ++k2) {
            const int kb2 = (k2 * 32 + g * 8) * 2;
            const bfrag pb = *(const bfrag*)(Pw + ((c * 128 + kb2) ^ ((c & 7) << 4)));
            #pragma unroll
            for (int mtl = 0; mtl < 8; ++mtl) {
                const int d = mtl * 16 + c;
                const bfrag va = *(const bfrag*)(Vsm + ((d * 128 + kb2) ^ ((d & 7) << 4)));
                oacc[mtl] = __builtin_amdgcn_mfma_f32_16x16x32_bf16(va, pb, oacc[mtl], 0, 0, 0);
            }
        }
    }

    {
        const int rr = c & 3;
        float inv[4];
        #pragma unroll
        for (int r = 0; r < 4; ++r) inv[r] = 1.f / lrun[r];
        float vsel = inv[0];
        vsel = (rr == 1) ? inv[1] : vsel;
        vsel = (rr == 2) ? inv[2] : vsel;
        vsel = (rr == 3) ? inv[3] : vsel;
        const float ic = __shfl(vsel, ((c >> 2) << 4) | (c & 3), 64);
        #pragma unroll
        for (int i = 0; i < 8; ++i) {
            oacc[i][0] *= ic; oacc[i][1] *= ic; oacc[i][2] *= ic; oacc[i][3] *= ic;
        }
    }
    __syncthreads();
    float* Ox = (float*)(smem + wv * 8192);
    #pragma unroll
    for (int mtl = 0; mtl < 8; ++mtl)
        #pragma unroll
        for (int r = 0; r < 4; ++r)
            Ox[(mtl * 16 + 4 * g + r) * 16 + c] = oacc[mtl][r];
    asm volatile("s_waitcnt lgkmcnt(0)" ::: "memory");
    __builtin_amdgcn_sched_barrier(0);

    const int q = lane >> 2, qt = lane & 3;
    const int colbase = (qt >> 1) * 512 + hh * 64 + (qt & 1) * 32;
    const size_t rowm = (size_t)bb * SEQ + q0 + wv * 16 + q;
    unsigned short* dst = Ah + rowm * KHAT + colbase;
    #pragma unroll
    for (int j = 0; j < 8; ++j) {
        us4 o;
        #pragma unroll
        for (int e = 0; e < 4; ++e) o[e] = f2bf(Ox[(qt * 32 + j * 4 + e) * 16 + q]);
        *(us4*)(dst + j * 4) = o;
    }
}

// ---------------------------------------------------------------- complex LayerNorm (+bf16 X̂ out)
__global__ __launch_bounds__(256)
void cln_kernel(const float* __restrict__ Ur, const float* __restrict__ Ui,
                float* __restrict__ Xr, float* __restrict__ Xi,
                unsigned short* __restrict__ Xh,
                const float* __restrict__ Grr, const float* __restrict__ Gri,
                const float* __restrict__ Gii, const float* __restrict__ Bbr,
                const float* __restrict__ Bbi)
{
    const int lane = threadIdx.x & 63;
    const int row  = blockIdx.x * 4 + (threadIdx.x >> 6);
    const size_t off = (size_t)row * DIM;
    const int c0 = lane * 4;
    const int c1 = 256 + lane * 4;

    float xr[8], xi[8];
    {
        float a[4], b[4];
        f4a(*(const float4*)&Ur[off + c0], a); f4a(*(const float4*)&Xr[off + c0], b);
        #pragma unroll
        for (int j = 0; j < 4; ++j) xr[j] = a[j] + b[j];
        f4a(*(const float4*)&Ur[off + c1], a); f4a(*(const float4*)&Xr[off + c1], b);
        #pragma unroll
        for (int j = 0; j < 4; ++j) xr[4 + j] = a[j] + b[j];
        f4a(*(const float4*)&Ui[off + c0], a); f4a(*(const float4*)&Xi[off + c0], b);
        #pragma unroll
        for (int j = 0; j < 4; ++j) xi[j] = a[j] + b[j];
        f4a(*(const float4*)&Ui[off + c1], a); f4a(*(const float4*)&Xi[off + c1], b);
        #pragma unroll
        for (int j = 0; j < 4; ++j) xi[4 + j] = a[j] + b[j];
    }

    float sr = 0.f, si = 0.f, srr = 0.f, sii = 0.f, sri = 0.f;
    #pragma unroll
    for (int j = 0; j < 8; ++j) {
        sr += xr[j]; si += xi[j];
        srr = fmaf(xr[j], xr[j], srr);
        sii = fmaf(xi[j], xi[j], sii);
        sri = fmaf(xr[j], xi[j], sri);
    }
    #pragma unroll
    for (int m = 32; m >= 1; m >>= 1) {
        sr  += __shfl_xor(sr,  m, 64);
        si  += __shfl_xor(si,  m, 64);
        srr += __shfl_xor(srr, m, 64);
        sii += __shfl_xor(sii, m, 64);
        sri += __shfl_xor(sri, m, 64);
    }

    const float inv_d = 1.0f / DIM;
    const float mr = sr * inv_d, mi = si * inv_d;
    const float Vrr = srr * inv_d - mr * mr + 1e-5f;
    const float Vii = sii * inv_d - mi * mi + 1e-5f;
    const float Vri = sri * inv_d - mr * mi;
    const float s  = sqrtf(Vrr * Vii - Vri * Vri);
    const float tt = sqrtf(Vrr + Vii + 2.0f * s);
    const float ist = 1.0f / (s * tt);
    const float Wrr = (Vii + s) * ist;
    const float Wii = (Vrr + s) * ist;
    const float Wri = -Vri * ist;

    #pragma unroll
    for (int half = 0; half < 2; ++half) {
        const int c = half ? c1 : c0;
        float grr[4], gri[4], gii[4], pbr[4], pbi[4];
        f4a(*(const float4*)&Grr[c], grr);
        f4a(*(const float4*)&Gri[c], gri);
        f4a(*(const float4*)&Gii[c], gii);
        f4a(*(const float4*)&Bbr[c], pbr);
        f4a(*(const float4*)&Bbi[c], pbi);
        float outr[4], outi[4];
        #pragma unroll
        for (int j = 0; j < 4; ++j) {
            const int idx = half * 4 + j;
            const float cr = xr[idx] - mr;
            const float ci = xi[idx] - mi;
            const float hr = Wrr * cr + Wri * ci;
            const float hi = Wri * cr + Wii * ci;
            outr[j] = fmaf(grr[j], hr, fmaf(gri[j], hi, pbr[j]));
            outi[j] = fmaf(gri[j], hr, fmaf(gii[j], hi, pbi[j]));
        }
        *(float4*)&Xr[off + c] = a4f(outr);
        *(float4*)&Xi[off + c] = a4f(outi);
        us4 hr_, hi_;
        #pragma unroll
        for (int j = 0; j < 4; ++j) { hr_[j] = f2bf(outr[j]); hi_[j] = f2bf(outi[j]); }
        *(us4*)(Xh + (size_t)row * KHAT + c)       = hr_;
        *(us4*)(Xh + (size_t)row * KHAT + 512 + c) = hi_;
    }
}

// ---------------------------------------------------------------- init: copy + bf16 X̂
__global__ __launch_bounds__(256)
void init_cvt(const float* __restrict__ xr, const float* __restrict__ xi,
              float* __restrict__ outr, float* __restrict__ outi,
              unsigned short* __restrict__ Xh)
{
    const size_t i = ((size_t)blockIdx.x * 256 + threadIdx.x) * 4;
    float vr[4], vi[4];
    f4a(*(const float4*)(xr + i), vr);
    f4a(*(const float4*)(xi + i), vi);
    *(float4*)(outr + i) = a4f(vr);
    *(float4*)(outi + i) = a4f(vi);
    const size_t m = i >> 9;
    const int k = (int)(i & 511);
    us4 a, b;
    #pragma unroll
    for (int j = 0; j < 4; ++j) { a[j] = f2bf(vr[j]); b[j] = f2bf(vi[j]); }
    *(us4*)(Xh + m * KHAT + k)       = a;
    *(us4*)(Xh + m * KHAT + 512 + k) = b;
}

// ---------------------------------------------------------------- host
extern "C" void kernel_launch(void* const* d_in, const int* in_sizes, int n_in,
                              void* d_out, int out_size, void* d_ws, size_t ws_size,
                              hipStream_t stream) {
    (void)in_sizes; (void)n_in; (void)out_size; (void)ws_size;

    const float* in_xr = (const float*)d_in[0];
    const float* in_xi = (const float*)d_in[1];
    PrepArgs pa;
    pa.Wr[0] = (const float*)d_in[2];  pa.Wi[0] = (const float*)d_in[3];   // q
    pa.Wr[1] = (const float*)d_in[4];  pa.Wi[1] = (const float*)d_in[5];   // k
    pa.Wr[2] = (const float*)d_in[6];  pa.Wi[2] = (const float*)d_in[7];   // v
    pa.Wr[3] = (const float*)d_in[8];  pa.Wi[3] = (const float*)d_in[9];   // o
    pa.Wr[4] = (const float*)d_in[10]; pa.Wi[4] = (const float*)d_in[11];  // f1
    pa.Wr[5] = (const float*)d_in[12]; pa.Wi[5] = (const float*)d_in[13];  // f2
    pa.br[0] = (const float*)d_in[14]; pa.bi[0] = (const float*)d_in[15];
    pa.br[1] = (const float*)d_in[16]; pa.bi[1] = (const float*)d_in[17];
    pa.br[2] = (const float*)d_in[18]; pa.bi[2] = (const float*)d_in[19];
    pa.br[3] = (const float*)d_in[20]; pa.bi[3] = (const float*)d_in[21];
    pa.br[4] = (const float*)d_in[22]; pa.bi[4] = (const float*)d_in[23];
    pa.br[5] = (const float*)d_in[24]; pa.bi[5] = (const float*)d_in[25];
    const float* ln1_grr = (const float*)d_in[26];
    const float* ln1_gii = (const float*)d_in[27];
    const float* ln2_grr = (const float*)d_in[28];
    const float* ln2_gii = (const float*)d_in[29];
    const float* ln1_gri = (const float*)d_in[30];
    const float* ln1_br  = (const float*)d_in[31];
    const float* ln1_bi  = (const float*)d_in[32];
    const float* ln2_gri = (const float*)d_in[33];
    const float* ln2_br  = (const float*)d_in[34];
    const float* ln2_bi  = (const float*)d_in[35];

    float* outr = (float*)d_out;
    float* outi = outr + BSD;

    char* ws = (char*)d_ws;
    unsigned short* Xh  = (unsigned short*)(ws);                    // 16.8 MB
    unsigned short* Qh  = (unsigned short*)(ws + 16777216);         // Q̂ / Ĥ
    unsigned short* Kh  = (unsigned short*)(ws + 2 * 16777216);     // K̂ / Pr
    unsigned short* Vth = (unsigned short*)(ws + 3 * 16777216);     // V̂t / Pi
    unsigned short* Ah  = (unsigned short*)(ws + 4 * 16777216);     // Â
    unsigned short* Ball = (unsigned short*)(ws + 5 * 16777216);    // 6 x 2 MB
    float* biasall = (float*)(ws + 5 * 16777216 + 12582912);        // 24 KB
    float* Pr = (float*)Kh;
    float* Pi = (float*)Vth;
    unsigned short* Hh = Qh;

    init_cvt<<<ROWS * DIM / 1024, 256, 0, stream>>>(in_xr, in_xi, outr, outi, Xh);

    const dim3 pgrid(KHAT, 6);
    const dim3 ggrid(KHAT / 128, ROWS / 128);   // (8, 64)
    const dim3 agrid(SEQ / 64, NH, NB);
    const int  lgrid = ROWS / 4;

    for (int l = 0; l < NL; ++l) {
        const size_t bo = (size_t)l * DIM;
        prep_kernel<<<pgrid, 256, 0, stream>>>(pa, Ball, biasall, l);

        unsigned short* Bq = Ball;
        unsigned short* Bk = Ball + (size_t)1 * KHAT * KHAT;
        unsigned short* Bv = Ball + (size_t)2 * KHAT * KHAT;
        unsigned short* Bo = Ball + (size_t)3 * KHAT * KHAT;
        unsigned short* B1 = Ball + (size_t)4 * KHAT * KHAT;
        unsigned short* B2 = Ball + (size_t)5 * KHAT * KHAT;

        gemm_mfma<0><<<ggrid, 256, 0, stream>>>(Xh, Bq, biasall + 0 * KHAT, Qh, nullptr, nullptr);
        gemm_mfma<0><<<ggrid, 256, 0, stream>>>(Xh, Bk, biasall + 1 * KHAT, Kh, nullptr, nullptr);
        gemm_mfma<1><<<ggrid, 256, 0, stream>>>(Xh, Bv, biasall + 2 * KHAT, Vth, nullptr, nullptr);
        attn_mfma<<<agrid, 256, 0, stream>>>(Qh, Kh, Vth, Ah);
        gemm_mfma<2><<<ggrid, 256, 0, stream>>>(Ah, Bo, biasall + 3 * KHAT, nullptr, Pr, Pi);
        cln_kernel<<<lgrid, 256, 0, stream>>>(Pr, Pi, outr, outi, Xh,
                                              ln1_grr + bo, ln1_gri + bo, ln1_gii + bo,
                                              ln1_br + bo, ln1_bi + bo);
        gemm_mfma<3><<<ggrid, 256, 0, stream>>>(Xh, B1, biasall + 4 * KHAT, Hh, nullptr, nullptr);
        gemm_mfma<2><<<ggrid, 256, 0, stream>>>(Hh, B2, biasall + 5 * KHAT, nullptr, Pr, Pi);
        cln_kernel<<<lgrid, 256, 0, stream>>>(Pr, Pi, outr, outi, Xh,
                                              ln2_grr + bo, ln2_gri + bo, ln2_gii + bo,
                                              ln2_br + bo, ln2_bi + bo);
    }
}

// Round 4
// 1706.224 us; speedup vs baseline: 7.5009x; 1.0785x over previous
//
#include <hip/hip_runtime.h>
#include <cstddef>
#include <cstdint>

// ---------------------------------------------------------------- constants
constexpr int NB   = 8;
constexpr int SEQ  = 1024;
constexpr int DIM  = 512;
constexpr int NL   = 6;
constexpr int NH   = 8;
constexpr int HDIM = 64;
constexpr int ROWS = NB * SEQ;               // 8192
constexpr size_t BSD = (size_t)ROWS * DIM;   // 4,194,304
constexpr int KHAT = 1024;                   // concat K dim

typedef __attribute__((ext_vector_type(8))) short bfrag;   // 8 bf16 = 16B
typedef __attribute__((ext_vector_type(4))) float f32x4;
typedef __attribute__((ext_vector_type(4))) unsigned short us4;

__device__ __forceinline__ void f4a(const float4 v, float* a) {
    a[0] = v.x; a[1] = v.y; a[2] = v.z; a[3] = v.w;
}
__device__ __forceinline__ float4 a4f(const float* a) {
    float4 v; v.x = a[0]; v.y = a[1]; v.z = a[2]; v.w = a[3]; return v;
}
__device__ __forceinline__ unsigned short f2bf(float f) {
    union { float f; uint32_t u; } x{f};
    return (unsigned short)((x.u + 0x7fffu + ((x.u >> 16) & 1u)) >> 16);
}
// async global->LDS DMA, 16B per lane; LDS dest = wave-uniform base + lane*16
__device__ __forceinline__ void gload16(const unsigned short* g, void* l) {
    __builtin_amdgcn_global_load_lds(
        (const __attribute__((address_space(1))) void*)g,
        (__attribute__((address_space(3))) void*)l, 16, 0, 0);
}

// ---------------------------------------------------------------- weight prep
struct PrepArgs {
    const float* Wr[6]; const float* Wi[6];
    const float* br[6]; const float* bi[6];
};

__global__ __launch_bounds__(256)
void prep_kernel(PrepArgs a, unsigned short* __restrict__ Ball,
                 float* __restrict__ biasall, int layer)
{
    const int lin = blockIdx.y;
    const int nh_ = blockIdx.x;           // ň
    const float* Wr = a.Wr[lin] + (size_t)layer * DIM * DIM;
    const float* Wi = a.Wi[lin] + (size_t)layer * DIM * DIM;

    bool real; int n0;
    if (lin < 3) { const int dh = nh_ & 127; real = dh < 64; n0 = (nh_ >> 7) * 64 + (dh & 63); }
    else         { real = nh_ < 512; n0 = nh_ & 511; }

    const int t = threadIdx.x;
    const int kk = (t * 4) & 511;
    const bool fh = t < 128;
    const float* src;
    float sgn = 1.f;
    if (fh) src = real ? Wr : Wi;
    else { if (real) { src = Wi; sgn = -1.f; } else src = Wr; }

    float v[4];
    f4a(*(const float4*)(src + (size_t)n0 * 512 + kk), v);
    us4 o;
    #pragma unroll
    for (int j = 0; j < 4; ++j) o[j] = f2bf(sgn * v[j]);
    *(us4*)(Ball + (size_t)lin * KHAT * KHAT + (size_t)nh_ * KHAT + t * 4) = o;
    if (t == 0)
        biasall[lin * KHAT + nh_] = real ? a.br[lin][layer * DIM + n0]
                                         : a.bi[lin][layer * DIM + n0];
}

// ---------------------------------------------------------------- MFMA GEMM (m97 structure)
//  Y[m][n] = Σ_k X̂[m][k] B̂[n][k] + bias[n];  M=8192, N=K=1024.
//  128x128 tile, BK=32, 4 waves (2x2), global_load_lds staging, XCD swizzle.
template <int EPI>
__global__ __launch_bounds__(256)
void gemm_mfma(const unsigned short* __restrict__ Xh,
               const unsigned short* __restrict__ Bh,
               const float* __restrict__ bias,
               unsigned short* __restrict__ Yh,
               float* __restrict__ Yr, float* __restrict__ Yi)
{
    __shared__ __align__(16) unsigned short Asm[128 * 32];
    __shared__ __align__(16) unsigned short Bsm[128 * 32];

    const int t = threadIdx.x, lane = t & 63, w = t >> 6;
    const int wm = w >> 1, wn = w & 1;
    const int c = lane & 15, g = lane >> 4;

    // XCD-bijective swizzle: 512 blocks, 8 XCDs, 64 per chunk -> each XCD
    // owns 8 consecutive M-panels (A panel 2MB + B 2MB fit its L2).
    int bid = blockIdx.y * 8 + blockIdx.x;
    bid = (bid & 7) * 64 + (bid >> 3);
    const int n0 = (bid & 7) * 128;
    const int m0 = (bid >> 3) * 128;

    f32x4 acc[4][4];
    #pragma unroll
    for (int i = 0; i < 4; ++i)
        #pragma unroll
        for (int j = 0; j < 4; ++j) acc[i][j] = (f32x4){0.f, 0.f, 0.f, 0.f};

    // staging map: wave w covers LDS bytes [w*1024,(w+1)*1024); lane l ->
    // row 16w + (l>>2), ushort col (l&3)*8  (matches linear [row][32] layout)
    const int srow = (w << 4) + (lane >> 2);
    const int scol = (lane & 3) * 8;
    const unsigned short* gA0 = Xh + (size_t)(m0 + srow) * KHAT + scol;
    const unsigned short* gA1 = Xh + (size_t)(m0 + 64 + srow) * KHAT + scol;
    const unsigned short* gB0 = Bh + (size_t)(n0 + srow) * KHAT + scol;
    const unsigned short* gB1 = Bh + (size_t)(n0 + 64 + srow) * KHAT + scol;
    char* aBase = (char*)Asm + (w << 10);
    char* bBase = (char*)Bsm + (w << 10);

    for (int ks = 0; ks < 32; ++ks) {
        const int k0 = ks * 32;
        __syncthreads();                    // all waves done reading LDS
        gload16(gA0 + k0, aBase);
        gload16(gA1 + k0, aBase + 4096);
        gload16(gB0 + k0, bBase);
        gload16(gB1 + k0, bBase + 4096);
        __syncthreads();                    // vmcnt(0) drain -> LDS ready

        bfrag af[4], bf2[4];
        #pragma unroll
        for (int mi = 0; mi < 4; ++mi)
            af[mi] = *(const bfrag*)(Asm + (wm * 64 + mi * 16 + c) * 32 + g * 8);
        #pragma unroll
        for (int ni = 0; ni < 4; ++ni)
            bf2[ni] = *(const bfrag*)(Bsm + (wn * 64 + ni * 16 + c) * 32 + g * 8);
        #pragma unroll
        for (int mi = 0; mi < 4; ++mi)
            #pragma unroll
            for (int ni = 0; ni < 4; ++ni)
                acc[mi][ni] = __builtin_amdgcn_mfma_f32_16x16x32_bf16(
                    af[mi], bf2[ni], acc[mi][ni], 0, 0, 0);
    }

    // ---- epilogue
    const int mbase = m0 + wm * 64;
    const int nbase = n0 + wn * 64;
    #pragma unroll
    for (int mi = 0; mi < 4; ++mi) {
        #pragma unroll
        for (int ni = 0; ni < 4; ++ni) {
            const int n = nbase + ni * 16 + c;
            const float bv = bias[n];
            float v[4];
            #pragma unroll
            for (int r = 0; r < 4; ++r) v[r] = acc[mi][ni][r] + bv;
            const int mrow = mbase + mi * 16 + g * 4;
            if (EPI == 0) {
                const int b = mrow >> 10, s = mrow & 1023;
                const int h = n >> 7, dh = n & 127;
                const size_t a = ((size_t)(b * NH + h) * SEQ + s) * 128 + dh;
                #pragma unroll
                for (int r = 0; r < 4; ++r) Yh[a + (size_t)r * 128] = f2bf(v[r]);
            } else if (EPI == 1) {
                const int b = mrow >> 10, s = mrow & 1023;
                const int h = n >> 7, dh = n & 127;
                const size_t a = ((size_t)(b * NH + h) * 128 + dh) * SEQ + s;
                us4 o;
                #pragma unroll
                for (int r = 0; r < 4; ++r) o[r] = f2bf(v[r]);
                *(us4*)(Yh + a) = o;
            } else if (EPI == 2) {
                float* dst = (n < 512) ? Yr : Yi;
                const int nn = n & 511;
                #pragma unroll
                for (int r = 0; r < 4; ++r) dst[(size_t)(mrow + r) * DIM + nn] = v[r];
            } else {
                #pragma unroll
                for (int r = 0; r < 4; ++r)
                    Yh[(size_t)(mrow + r) * KHAT + n] = f2bf(fmaxf(v[r], 0.f));
            }
        }
    }
}

// ---------------------------------------------------------------- MFMA flash attention
//  T14 async-stage (next tile loads issued under compute), T13 defer-max,
//  T5 setprio, XCD-bijective swizzle.
__global__ __launch_bounds__(256)
void attn_mfma(const unsigned short* __restrict__ Qh,
               const unsigned short* __restrict__ Kh,
               const unsigned short* __restrict__ Vth,
               unsigned short* __restrict__ Ah)
{
    __shared__ __align__(16) char smem[41216];
    char* Ksm = smem;
    char* Vsm = smem + 16384;
    const int t    = threadIdx.x;
    const int lane = t & 63;
    const int wv   = t >> 6;
    const int c    = lane & 15;
    const int g    = lane >> 4;
    char* Pw = smem + 32768 + wv * 2048;

    // 1024 blocks; each XCD chunk = 128 = 8 (b,h) pairs -> K/V L2-local
    int bid = blockIdx.x + 16 * blockIdx.y + 128 * blockIdx.z;
    bid = (bid & 7) * 128 + (bid >> 3);
    const int q0 = (bid & 15) * 64;
    const int bh = bid >> 4;
    const int hh = bh & 7, bb = bh >> 3;
    const size_t qkb = (size_t)bh * SEQ * 128;
    const size_t vtb = (size_t)bh * 128 * SEQ;

    bfrag qf[4];
    {
        const unsigned short* qp = Qh + qkb + (size_t)(q0 + wv * 16 + c) * 128 + g * 8;
        #pragma unroll
        for (int ks = 0; ks < 4; ++ks) qf[ks] = *(const bfrag*)(qp + ks * 32);
    }

    f32x4 oacc[8];
    #pragma unroll
    for (int i = 0; i < 8; ++i) oacc[i] = (f32x4){0.f, 0.f, 0.f, 0.f};
    float mrun[4], lrun[4];
    #pragma unroll
    for (int r = 0; r < 4; ++r) { mrun[r] = -1e30f; lrun[r] = 0.f; }

    const int kkey = t >> 2, kq = t & 3;
    const unsigned short* kgp = Kh + qkb + (size_t)kkey * 128 + kq * 32;
    const int vd = t >> 1, vh2 = t & 1;
    const unsigned short* vgp = Vth + vtb + (size_t)vd * SEQ + vh2 * 32;

    // preload tile 0
    bfrag krg[4], vrg[4];
    #pragma unroll
    for (int j = 0; j < 4; ++j) krg[j] = *(const bfrag*)(kgp + j * 8);
    #pragma unroll
    for (int j = 0; j < 4; ++j) vrg[j] = *(const bfrag*)(vgp + j * 8);

    for (int k0 = 0; k0 < SEQ; k0 += 64) {
        __syncthreads();   // prior-iter LDS reads done
        #pragma unroll
        for (int j = 0; j < 4; ++j) {
            const int boff = (kkey * 256 + (kq * 32 + j * 8) * 2) ^ ((kkey & 7) << 4);
            *(bfrag*)(Ksm + boff) = krg[j];
        }
        #pragma unroll
        for (int j = 0; j < 4; ++j) {
            const int boff = (vd * 128 + (vh2 * 32 + j * 8) * 2) ^ ((vd & 7) << 4);
            *(bfrag*)(Vsm + boff) = vrg[j];
        }
        __syncthreads();

        // T14: issue next-tile loads now; latency hides under QK+softmax+PV
        if (k0 + 64 < SEQ) {
            const int kn = k0 + 64;
            #pragma unroll
            for (int j = 0; j < 4; ++j) krg[j] = *(const bfrag*)(kgp + (size_t)kn * 128 + j * 8);
            #pragma unroll
            for (int j = 0; j < 4; ++j) vrg[j] = *(const bfrag*)(vgp + kn + j * 8);
        }

        // ---- S = Q̂ · K̂ᵀ
        f32x4 sa[4];
        #pragma unroll
        for (int nt = 0; nt < 4; ++nt) sa[nt] = (f32x4){0.f, 0.f, 0.f, 0.f};
        __builtin_amdgcn_s_setprio(1);
        #pragma unroll
        for (int nt = 0; nt < 4; ++nt) {
            const int key = nt * 16 + c;
            #pragma unroll
            for (int ks = 0; ks < 4; ++ks) {
                const int boff = (key * 256 + (ks * 32 + g * 8) * 2) ^ ((key & 7) << 4);
                const bfrag bk = *(const bfrag*)(Ksm + boff);
                sa[nt] = __builtin_amdgcn_mfma_f32_16x16x32_bf16(qf[ks], bk, sa[nt], 0, 0, 0);
            }
        }
        __builtin_amdgcn_s_setprio(0);

        float sv[4][4];
        #pragma unroll
        for (int nt = 0; nt < 4; ++nt)
            #pragma unroll
            for (int r = 0; r < 4; ++r) sv[nt][r] = sa[nt][r] * 0.125f;

        float mt[4], ps[4], mn[4];
        #pragma unroll
        for (int r = 0; r < 4; ++r)
            mt[r] = fmaxf(fmaxf(sv[0][r], sv[1][r]), fmaxf(sv[2][r], sv[3][r]));
        #pragma unroll
        for (int m = 1; m <= 8; m <<= 1) {
            #pragma unroll
            for (int r = 0; r < 4; ++r) mt[r] = fmaxf(mt[r], __shfl_xor(mt[r], m, 64));
        }
        // T13 defer-max: only rescale when some row max grew by > 8
        bool big = false;
        #pragma unroll
        for (int r = 0; r < 4; ++r) big |= (mt[r] > mrun[r] + 8.f);
        const bool refresh = __any(big);
        float fs[4];
        if (refresh) {
            #pragma unroll
            for (int r = 0; r < 4; ++r) {
                mn[r] = fmaxf(mrun[r], mt[r]);
                fs[r] = __expf(mrun[r] - mn[r]);
            }
        } else {
            #pragma unroll
            for (int r = 0; r < 4; ++r) { mn[r] = mrun[r]; fs[r] = 1.f; }
        }
        #pragma unroll
        for (int r = 0; r < 4; ++r) ps[r] = 0.f;

        #pragma unroll
        for (int nt = 0; nt < 4; ++nt) {
            const int col2 = (nt * 16 + c) * 2;
            #pragma unroll
            for (int r = 0; r < 4; ++r) {
                const float p = __expf(sv[nt][r] - mn[r]);
                ps[r] += p;
                const int qrow = 4 * g + r;
                *(unsigned short*)(Pw + ((qrow * 128 + col2) ^ ((qrow & 7) << 4))) = f2bf(p);
            }
        }
        #pragma unroll
        for (int m = 1; m <= 8; m <<= 1) {
            #pragma unroll
            for (int r = 0; r < 4; ++r) ps[r] += __shfl_xor(ps[r], m, 64);
        }
        #pragma unroll
        for (int r = 0; r < 4; ++r) {
            lrun[r] = lrun[r] * fs[r] + ps[r];
            mrun[r] = mn[r];
        }

        if (refresh) {   // O-rescale only on refresh
            const int rr = c & 3;
            float vsel = fs[0];
            vsel = (rr == 1) ? fs[1] : vsel;
            vsel = (rr == 2) ? fs[2] : vsel;
            vsel = (rr == 3) ? fs[3] : vsel;
            const float fsc = __shfl(vsel, ((c >> 2) << 4) | (c & 3), 64);
            #pragma unroll
            for (int i = 0; i < 8; ++i) {
                oacc[i][0] *= fsc; oacc[i][1] *= fsc; oacc[i][2] *= fsc; oacc[i][3] *= fsc;
            }
        }

        asm volatile("s_waitcnt lgkmcnt(0)" ::: "memory");
        __builtin_amdgcn_sched_barrier(0);

        // ---- Oᵀ += V̂ᵀ · Pᵀ
        __builtin_amdgcn_s_setprio(1);
        #pragma unroll
        for (int k2 = 0; k2 < 2; ++k2) {
            const int kb2 = (k2 * 32 + g * 8) * 2;
            const bfrag pb = *(const bfrag*)(Pw + ((c * 128 + kb2) ^ ((c & 7) << 4)));
            #pragma unroll
            for (int mtl = 0; mtl < 8; ++mtl) {
                const int d = mtl * 16 + c;
                const bfrag va = *(const bfrag*)(Vsm + ((d * 128 + kb2) ^ ((d & 7) << 4)));
                oacc[mtl] = __builtin_amdgcn_mfma_f32_16x16x32_bf16(va, pb, oacc[mtl], 0, 0, 0);
            }
        }
        __builtin_amdgcn_s_setprio(0);
    }

    {
        const int rr = c & 3;
        float inv[4];
        #pragma unroll
        for (int r = 0; r < 4; ++r) inv[r] = 1.f / lrun[r];
        float vsel = inv[0];
        vsel = (rr == 1) ? inv[1] : vsel;
        vsel = (rr == 2) ? inv[2] : vsel;
        vsel = (rr == 3) ? inv[3] : vsel;
        const float ic = __shfl(vsel, ((c >> 2) << 4) | (c & 3), 64);
        #pragma unroll
        for (int i = 0; i < 8; ++i) {
            oacc[i][0] *= ic; oacc[i][1] *= ic; oacc[i][2] *= ic; oacc[i][3] *= ic;
        }
    }
    __syncthreads();
    float* Ox = (float*)(smem + wv * 8192);
    #pragma unroll
    for (int mtl = 0; mtl < 8; ++mtl)
        #pragma unroll
        for (int r = 0; r < 4; ++r)
            Ox[(mtl * 16 + 4 * g + r) * 16 + c] = oacc[mtl][r];
    asm volatile("s_waitcnt lgkmcnt(0)" ::: "memory");
    __builtin_amdgcn_sched_barrier(0);

    const int q = lane >> 2, qt = lane & 3;
    const int colbase = (qt >> 1) * 512 + hh * 64 + (qt & 1) * 32;
    const size_t rowm = (size_t)bb * SEQ + q0 + wv * 16 + q;
    unsigned short* dst = Ah + rowm * KHAT + colbase;
    #pragma unroll
    for (int j = 0; j < 8; ++j) {
        us4 o;
        #pragma unroll
        for (int e = 0; e < 4; ++e) o[e] = f2bf(Ox[(qt * 32 + j * 4 + e) * 16 + q]);
        *(us4*)(dst + j * 4) = o;
    }
}

// ---------------------------------------------------------------- complex LayerNorm (+bf16 X̂ out)
__global__ __launch_bounds__(256)
void cln_kernel(const float* __restrict__ Ur, const float* __restrict__ Ui,
                float* __restrict__ Xr, float* __restrict__ Xi,
                unsigned short* __restrict__ Xh,
                const float* __restrict__ Grr, const float* __restrict__ Gri,
                const float* __restrict__ Gii, const float* __restrict__ Bbr,
                const float* __restrict__ Bbi)
{
    const int lane = threadIdx.x & 63;
    const int row  = blockIdx.x * 4 + (threadIdx.x >> 6);
    const size_t off = (size_t)row * DIM;
    const int c0 = lane * 4;
    const int c1 = 256 + lane * 4;

    float xr[8], xi[8];
    {
        float a[4], b[4];
        f4a(*(const float4*)&Ur[off + c0], a); f4a(*(const float4*)&Xr[off + c0], b);
        #pragma unroll
        for (int j = 0; j < 4; ++j) xr[j] = a[j] + b[j];
        f4a(*(const float4*)&Ur[off + c1], a); f4a(*(const float4*)&Xr[off + c1], b);
        #pragma unroll
        for (int j = 0; j < 4; ++j) xr[4 + j] = a[j] + b[j];
        f4a(*(const float4*)&Ui[off + c0], a); f4a(*(const float4*)&Xi[off + c0], b);
        #pragma unroll
        for (int j = 0; j < 4; ++j) xi[j] = a[j] + b[j];
        f4a(*(const float4*)&Ui[off + c1], a); f4a(*(const float4*)&Xi[off + c1], b);
        #pragma unroll
        for (int j = 0; j < 4; ++j) xi[4 + j] = a[j] + b[j];
    }

    float sr = 0.f, si = 0.f, srr = 0.f, sii = 0.f, sri = 0.f;
    #pragma unroll
    for (int j = 0; j < 8; ++j) {
        sr += xr[j]; si += xi[j];
        srr = fmaf(xr[j], xr[j], srr);
        sii = fmaf(xi[j], xi[j], sii);
        sri = fmaf(xr[j], xi[j], sri);
    }
    #pragma unroll
    for (int m = 32; m >= 1; m >>= 1) {
        sr  += __shfl_xor(sr,  m, 64);
        si  += __shfl_xor(si,  m, 64);
        srr += __shfl_xor(srr, m, 64);
        sii += __shfl_xor(sii, m, 64);
        sri += __shfl_xor(sri, m, 64);
    }

    const float inv_d = 1.0f / DIM;
    const float mr = sr * inv_d, mi = si * inv_d;
    const float Vrr = srr * inv_d - mr * mr + 1e-5f;
    const float Vii = sii * inv_d - mi * mi + 1e-5f;
    const float Vri = sri * inv_d - mr * mi;
    const float s  = sqrtf(Vrr * Vii - Vri * Vri);
    const float tt = sqrtf(Vrr + Vii + 2.0f * s);
    const float ist = 1.0f / (s * tt);
    const float Wrr = (Vii + s) * ist;
    const float Wii = (Vrr + s) * ist;
    const float Wri = -Vri * ist;

    #pragma unroll
    for (int half = 0; half < 2; ++half) {
        const int c = half ? c1 : c0;
        float grr[4], gri[4], gii[4], pbr[4], pbi[4];
        f4a(*(const float4*)&Grr[c], grr);
        f4a(*(const float4*)&Gri[c], gri);
        f4a(*(const float4*)&Gii[c], gii);
        f4a(*(const float4*)&Bbr[c], pbr);
        f4a(*(const float4*)&Bbi[c], pbi);
        float outr[4], outi[4];
        #pragma unroll
        for (int j = 0; j < 4; ++j) {
            const int idx = half * 4 + j;
            const float cr = xr[idx] - mr;
            const float ci = xi[idx] - mi;
            const float hr = Wrr * cr + Wri * ci;
            const float hi = Wri * cr + Wii * ci;
            outr[j] = fmaf(grr[j], hr, fmaf(gri[j], hi, pbr[j]));
            outi[j] = fmaf(gri[j], hr, fmaf(gii[j], hi, pbi[j]));
        }
        *(float4*)&Xr[off + c] = a4f(outr);
        *(float4*)&Xi[off + c] = a4f(outi);
        us4 hr_, hi_;
        #pragma unroll
        for (int j = 0; j < 4; ++j) { hr_[j] = f2bf(outr[j]); hi_[j] = f2bf(outi[j]); }
        *(us4*)(Xh + (size_t)row * KHAT + c)       = hr_;
        *(us4*)(Xh + (size_t)row * KHAT + 512 + c) = hi_;
    }
}

// ---------------------------------------------------------------- init: copy + bf16 X̂
__global__ __launch_bounds__(256)
void init_cvt(const float* __restrict__ xr, const float* __restrict__ xi,
              float* __restrict__ outr, float* __restrict__ outi,
              unsigned short* __restrict__ Xh)
{
    const size_t i = ((size_t)blockIdx.x * 256 + threadIdx.x) * 4;
    float vr[4], vi[4];
    f4a(*(const float4*)(xr + i), vr);
    f4a(*(const float4*)(xi + i), vi);
    *(float4*)(outr + i) = a4f(vr);
    *(float4*)(outi + i) = a4f(vi);
    const size_t m = i >> 9;
    const int k = (int)(i & 511);
    us4 a, b;
    #pragma unroll
    for (int j = 0; j < 4; ++j) { a[j] = f2bf(vr[j]); b[j] = f2bf(vi[j]); }
    *(us4*)(Xh + m * KHAT + k)       = a;
    *(us4*)(Xh + m * KHAT + 512 + k) = b;
}

// ---------------------------------------------------------------- host
extern "C" void kernel_launch(void* const* d_in, const int* in_sizes, int n_in,
                              void* d_out, int out_size, void* d_ws, size_t ws_size,
                              hipStream_t stream) {
    (void)in_sizes; (void)n_in; (void)out_size; (void)ws_size;

    const float* in_xr = (const float*)d_in[0];
    const float* in_xi = (const float*)d_in[1];
    PrepArgs pa;
    pa.Wr[0] = (const float*)d_in[2];  pa.Wi[0] = (const float*)d_in[3];   // q
    pa.Wr[1] = (const float*)d_in[4];  pa.Wi[1] = (const float*)d_in[5];   // k
    pa.Wr[2] = (const float*)d_in[6];  pa.Wi[2] = (const float*)d_in[7];   // v
    pa.Wr[3] = (const float*)d_in[8];  pa.Wi[3] = (const float*)d_in[9];   // o
    pa.Wr[4] = (const float*)d_in[10]; pa.Wi[4] = (const float*)d_in[11];  // f1
    pa.Wr[5] = (const float*)d_in[12]; pa.Wi[5] = (const float*)d_in[13];  // f2
    pa.br[0] = (const float*)d_in[14]; pa.bi[0] = (const float*)d_in[15];
    pa.br[1] = (const float*)d_in[16]; pa.bi[1] = (const float*)d_in[17];
    pa.br[2] = (const float*)d_in[18]; pa.bi[2] = (const float*)d_in[19];
    pa.br[3] = (const float*)d_in[20]; pa.bi[3] = (const float*)d_in[21];
    pa.br[4] = (const float*)d_in[22]; pa.bi[4] = (const float*)d_in[23];
    pa.br[5] = (const float*)d_in[24]; pa.bi[5] = (const float*)d_in[25];
    const float* ln1_grr = (const float*)d_in[26];
    const float* ln1_gii = (const float*)d_in[27];
    const float* ln2_grr = (const float*)d_in[28];
    const float* ln2_gii = (const float*)d_in[29];
    const float* ln1_gri = (const float*)d_in[30];
    const float* ln1_br  = (const float*)d_in[31];
    const float* ln1_bi  = (const float*)d_in[32];
    const float* ln2_gri = (const float*)d_in[33];
    const float* ln2_br  = (const float*)d_in[34];
    const float* ln2_bi  = (const float*)d_in[35];

    float* outr = (float*)d_out;
    float* outi = outr + BSD;

    char* ws = (char*)d_ws;
    unsigned short* Xh  = (unsigned short*)(ws);                    // 16.8 MB
    unsigned short* Qh  = (unsigned short*)(ws + 16777216);         // Q̂ / Ĥ
    unsigned short* Kh  = (unsigned short*)(ws + 2 * 16777216);     // K̂ / Pr
    unsigned short* Vth = (unsigned short*)(ws + 3 * 16777216);     // V̂t / Pi
    unsigned short* Ah  = (unsigned short*)(ws + 4 * 16777216);     // Â
    unsigned short* Ball = (unsigned short*)(ws + 5 * 16777216);    // 6 x 2 MB
    float* biasall = (float*)(ws + 5 * 16777216 + 12582912);        // 24 KB
    float* Pr = (float*)Kh;
    float* Pi = (float*)Vth;
    unsigned short* Hh = Qh;

    init_cvt<<<ROWS * DIM / 1024, 256, 0, stream>>>(in_xr, in_xi, outr, outi, Xh);

    const dim3 pgrid(KHAT, 6);
    const dim3 ggrid(KHAT / 128, ROWS / 128);   // (8, 64)
    const dim3 agrid(SEQ / 64, NH, NB);
    const int  lgrid = ROWS / 4;

    for (int l = 0; l < NL; ++l) {
        const size_t bo = (size_t)l * DIM;
        prep_kernel<<<pgrid, 256, 0, stream>>>(pa, Ball, biasall, l);

        unsigned short* Bq = Ball;
        unsigned short* Bk = Ball + (size_t)1 * KHAT * KHAT;
        unsigned short* Bv = Ball + (size_t)2 * KHAT * KHAT;
        unsigned short* Bo = Ball + (size_t)3 * KHAT * KHAT;
        unsigned short* B1 = Ball + (size_t)4 * KHAT * KHAT;
        unsigned short* B2 = Ball + (size_t)5 * KHAT * KHAT;

        gemm_mfma<0><<<ggrid, 256, 0, stream>>>(Xh, Bq, biasall + 0 * KHAT, Qh, nullptr, nullptr);
        gemm_mfma<0><<<ggrid, 256, 0, stream>>>(Xh, Bk, biasall + 1 * KHAT, Kh, nullptr, nullptr);
        gemm_mfma<1><<<ggrid, 256, 0, stream>>>(Xh, Bv, biasall + 2 * KHAT, Vth, nullptr, nullptr);
        attn_mfma<<<agrid, 256, 0, stream>>>(Qh, Kh, Vth, Ah);
        gemm_mfma<2><<<ggrid, 256, 0, stream>>>(Ah, Bo, biasall + 3 * KHAT, nullptr, Pr, Pi);
        cln_kernel<<<lgrid, 256, 0, stream>>>(Pr, Pi, outr, outi, Xh,
                                              ln1_grr + bo, ln1_gri + bo, ln1_gii + bo,
                                              ln1_br + bo, ln1_bi + bo);
        gemm_mfma<3><<<ggrid, 256, 0, stream>>>(Xh, B1, biasall + 4 * KHAT, Hh, nullptr, nullptr);
        gemm_mfma<2><<<ggrid, 256, 0, stream>>>(Hh, B2, biasall + 5 * KHAT, nullptr, Pr, Pi);
        cln_kernel<<<lgrid, 256, 0, stream>>>(Pr, Pi, outr, outi, Xh,
                                              ln2_grr + bo, ln2_gri + bo, ln2_gii + bo,
                                              ln2_br + bo, ln2_bi + bo);
    }
}

// Round 5
// 1515.589 us; speedup vs baseline: 8.4444x; 1.1258x over previous
//
#include <hip/hip_runtime.h>
#include <cstddef>
#include <cstdint>

// ---------------------------------------------------------------- constants
constexpr int NB   = 8;
constexpr int SEQ  = 1024;
constexpr int DIM  = 512;
constexpr int NL   = 6;
constexpr int NH   = 8;
constexpr int HDIM = 64;
constexpr int ROWS = NB * SEQ;               // 8192
constexpr size_t BSD = (size_t)ROWS * DIM;   // 4,194,304
constexpr int KHAT = 1024;                   // concat K dim

typedef __attribute__((ext_vector_type(8))) short bfrag;   // 8 bf16 = 16B
typedef __attribute__((ext_vector_type(4))) float f32x4;
typedef __attribute__((ext_vector_type(4))) unsigned short us4;

__device__ __forceinline__ void f4a(const float4 v, float* a) {
    a[0] = v.x; a[1] = v.y; a[2] = v.z; a[3] = v.w;
}
__device__ __forceinline__ float4 a4f(const float* a) {
    float4 v; v.x = a[0]; v.y = a[1]; v.z = a[2]; v.w = a[3]; return v;
}
__device__ __forceinline__ unsigned short f2bf(float f) {
    union { float f; uint32_t u; } x{f};
    return (unsigned short)((x.u + 0x7fffu + ((x.u >> 16) & 1u)) >> 16);
}
__device__ __forceinline__ float bf2f(unsigned short u) {
    union { uint32_t u; float f; } x;
    x.u = (uint32_t)u << 16;
    return x.f;
}
// async global->LDS DMA, 16B per lane; LDS dest = wave-uniform base + lane*16
__device__ __forceinline__ void gload16(const unsigned short* g, void* l) {
    __builtin_amdgcn_global_load_lds(
        (const __attribute__((address_space(1))) void*)g,
        (__attribute__((address_space(3))) void*)l, 16, 0, 0);
}

// ---------------------------------------------------------------- weight prep
struct PrepArgs {
    const float* Wr[6]; const float* Wi[6];
    const float* br[6]; const float* bi[6];
};

__global__ __launch_bounds__(256)
void prep_kernel(PrepArgs a, unsigned short* __restrict__ Ball,
                 float* __restrict__ biasall, int layer)
{
    const int lin = blockIdx.y;
    const int nh_ = blockIdx.x;           // ň
    const float* Wr = a.Wr[lin] + (size_t)layer * DIM * DIM;
    const float* Wi = a.Wi[lin] + (size_t)layer * DIM * DIM;

    bool real; int n0;
    if (lin < 3) { const int dh = nh_ & 127; real = dh < 64; n0 = (nh_ >> 7) * 64 + (dh & 63); }
    else         { real = nh_ < 512; n0 = nh_ & 511; }

    const int t = threadIdx.x;
    const int kk = (t * 4) & 511;
    const bool fh = t < 128;
    const float* src;
    float sgn = 1.f;
    if (fh) src = real ? Wr : Wi;
    else { if (real) { src = Wi; sgn = -1.f; } else src = Wr; }

    float v[4];
    f4a(*(const float4*)(src + (size_t)n0 * 512 + kk), v);
    us4 o;
    #pragma unroll
    for (int j = 0; j < 4; ++j) o[j] = f2bf(sgn * v[j]);
    *(us4*)(Ball + (size_t)lin * KHAT * KHAT + (size_t)nh_ * KHAT + t * 4) = o;
    if (t == 0)
        biasall[lin * KHAT + nh_] = real ? a.br[lin][layer * DIM + n0]
                                         : a.bi[lin][layer * DIM + n0];
}

// ---------------------------------------------------------------- fused QKV GEMM
//  One launch, N=3072 (Q|K|V). 128x128 tiles, BK=32, global_load_lds.
__global__ __launch_bounds__(256)
void gemm_qkv(const unsigned short* __restrict__ Xh,
              const unsigned short* __restrict__ Ball,
              const float* __restrict__ biasall,
              unsigned short* __restrict__ Qh,
              unsigned short* __restrict__ Kh,
              unsigned short* __restrict__ Vth)
{
    __shared__ __align__(16) unsigned short Asm[128 * 32];
    __shared__ __align__(16) unsigned short Bsm[128 * 32];

    const int t = threadIdx.x, lane = t & 63, w = t >> 6;
    const int wm = w >> 1, wn = w & 1;
    const int c = lane & 15, g = lane >> 4;

    // 1536 blocks, 8 XCD chunks of 192; n cycles fastest within a chunk
    int bid = blockIdx.y * 24 + blockIdx.x;
    bid = (bid & 7) * 192 + (bid >> 3);
    const int nblk = bid % 24, mblk = bid / 24;
    const int n0g = nblk * 128;          // 0..3071
    const int m0 = mblk * 128;
    const int lin = n0g >> 10;           // 0=Q 1=K 2=V
    const int n0 = n0g & 1023;
    const unsigned short* Bh = Ball + (size_t)lin * KHAT * KHAT;
    const float* bias = biasall + lin * KHAT;

    f32x4 acc[4][4];
    #pragma unroll
    for (int i = 0; i < 4; ++i)
        #pragma unroll
        for (int j = 0; j < 4; ++j) acc[i][j] = (f32x4){0.f, 0.f, 0.f, 0.f};

    const int srow = (w << 4) + (lane >> 2);
    const int scol = (lane & 3) * 8;
    const unsigned short* gA0 = Xh + (size_t)(m0 + srow) * KHAT + scol;
    const unsigned short* gA1 = Xh + (size_t)(m0 + 64 + srow) * KHAT + scol;
    const unsigned short* gB0 = Bh + (size_t)(n0 + srow) * KHAT + scol;
    const unsigned short* gB1 = Bh + (size_t)(n0 + 64 + srow) * KHAT + scol;
    char* aBase = (char*)Asm + (w << 10);
    char* bBase = (char*)Bsm + (w << 10);

    for (int ks = 0; ks < 32; ++ks) {
        const int k0 = ks * 32;
        __syncthreads();
        gload16(gA0 + k0, aBase);
        gload16(gA1 + k0, aBase + 4096);
        gload16(gB0 + k0, bBase);
        gload16(gB1 + k0, bBase + 4096);
        __syncthreads();

        bfrag af[4], bf2[4];
        #pragma unroll
        for (int mi = 0; mi < 4; ++mi)
            af[mi] = *(const bfrag*)(Asm + (wm * 64 + mi * 16 + c) * 32 + g * 8);
        #pragma unroll
        for (int ni = 0; ni < 4; ++ni)
            bf2[ni] = *(const bfrag*)(Bsm + (wn * 64 + ni * 16 + c) * 32 + g * 8);
        #pragma unroll
        for (int mi = 0; mi < 4; ++mi)
            #pragma unroll
            for (int ni = 0; ni < 4; ++ni)
                acc[mi][ni] = __builtin_amdgcn_mfma_f32_16x16x32_bf16(
                    af[mi], bf2[ni], acc[mi][ni], 0, 0, 0);
    }

    const int mbase = m0 + wm * 64;
    const int nbase = n0 + wn * 64;
    unsigned short* dqk = (lin == 0) ? Qh : Kh;
    #pragma unroll
    for (int mi = 0; mi < 4; ++mi) {
        #pragma unroll
        for (int ni = 0; ni < 4; ++ni) {
            const int n = nbase + ni * 16 + c;
            const float bv = bias[n];
            float v[4];
            #pragma unroll
            for (int r = 0; r < 4; ++r) v[r] = acc[mi][ni][r] + bv;
            const int mrow = mbase + mi * 16 + g * 4;
            const int b = mrow >> 10, s = mrow & 1023;
            const int h = n >> 7, dh = n & 127;
            if (lin < 2) {
                const size_t a = ((size_t)(b * NH + h) * SEQ + s) * 128 + dh;
                #pragma unroll
                for (int r = 0; r < 4; ++r) dqk[a + (size_t)r * 128] = f2bf(v[r]);
            } else {
                const size_t a = ((size_t)(b * NH + h) * 128 + dh) * SEQ + s;
                us4 o;
                #pragma unroll
                for (int r = 0; r < 4; ++r) o[r] = f2bf(v[r]);
                *(us4*)(Vth + a) = o;
            }
        }
    }
}

// ---------------------------------------------------------------- MFMA GEMM (bf16 out)
//  Y[m][n] = Σ_k X̂[m][k] B̂[n][k] + bias[n] -> bf16 [m][1024], optional CReLU.
template <bool RELU>
__global__ __launch_bounds__(256)
void gemm_mfma(const unsigned short* __restrict__ Xh,
               const unsigned short* __restrict__ Bh,
               const float* __restrict__ bias,
               unsigned short* __restrict__ Yh)
{
    __shared__ __align__(16) unsigned short Asm[128 * 32];
    __shared__ __align__(16) unsigned short Bsm[128 * 32];

    const int t = threadIdx.x, lane = t & 63, w = t >> 6;
    const int wm = w >> 1, wn = w & 1;
    const int c = lane & 15, g = lane >> 4;

    int bid = blockIdx.y * 8 + blockIdx.x;
    bid = (bid & 7) * 64 + (bid >> 3);
    const int n0 = (bid & 7) * 128;
    const int m0 = (bid >> 3) * 128;

    f32x4 acc[4][4];
    #pragma unroll
    for (int i = 0; i < 4; ++i)
        #pragma unroll
        for (int j = 0; j < 4; ++j) acc[i][j] = (f32x4){0.f, 0.f, 0.f, 0.f};

    const int srow = (w << 4) + (lane >> 2);
    const int scol = (lane & 3) * 8;
    const unsigned short* gA0 = Xh + (size_t)(m0 + srow) * KHAT + scol;
    const unsigned short* gA1 = Xh + (size_t)(m0 + 64 + srow) * KHAT + scol;
    const unsigned short* gB0 = Bh + (size_t)(n0 + srow) * KHAT + scol;
    const unsigned short* gB1 = Bh + (size_t)(n0 + 64 + srow) * KHAT + scol;
    char* aBase = (char*)Asm + (w << 10);
    char* bBase = (char*)Bsm + (w << 10);

    for (int ks = 0; ks < 32; ++ks) {
        const int k0 = ks * 32;
        __syncthreads();
        gload16(gA0 + k0, aBase);
        gload16(gA1 + k0, aBase + 4096);
        gload16(gB0 + k0, bBase);
        gload16(gB1 + k0, bBase + 4096);
        __syncthreads();

        bfrag af[4], bf2[4];
        #pragma unroll
        for (int mi = 0; mi < 4; ++mi)
            af[mi] = *(const bfrag*)(Asm + (wm * 64 + mi * 16 + c) * 32 + g * 8);
        #pragma unroll
        for (int ni = 0; ni < 4; ++ni)
            bf2[ni] = *(const bfrag*)(Bsm + (wn * 64 + ni * 16 + c) * 32 + g * 8);
        #pragma unroll
        for (int mi = 0; mi < 4; ++mi)
            #pragma unroll
            for (int ni = 0; ni < 4; ++ni)
                acc[mi][ni] = __builtin_amdgcn_mfma_f32_16x16x32_bf16(
                    af[mi], bf2[ni], acc[mi][ni], 0, 0, 0);
    }

    const int mbase = m0 + wm * 64;
    const int nbase = n0 + wn * 64;
    #pragma unroll
    for (int mi = 0; mi < 4; ++mi) {
        #pragma unroll
        for (int ni = 0; ni < 4; ++ni) {
            const int n = nbase + ni * 16 + c;
            const float bv = bias[n];
            const int mrow = mbase + mi * 16 + g * 4;
            #pragma unroll
            for (int r = 0; r < 4; ++r) {
                float v = acc[mi][ni][r] + bv;
                if (RELU) v = fmaxf(v, 0.f);
                Yh[(size_t)(mrow + r) * KHAT + n] = f2bf(v);
            }
        }
    }
}

// ---------------------------------------------------------------- MFMA flash attention
//  exp2 domain; l via ones-MFMA (9th accumulator, C-layout == O's);
//  local-max gate (cross-lane max reduce only on refresh); T14 prefetch; T5.
__global__ __launch_bounds__(256)
void attn_mfma(const unsigned short* __restrict__ Qh,
               const unsigned short* __restrict__ Kh,
               const unsigned short* __restrict__ Vth,
               unsigned short* __restrict__ Ah)
{
    __shared__ __align__(16) char smem[41216];
    char* Ksm = smem;
    char* Vsm = smem + 16384;
    const int t    = threadIdx.x;
    const int lane = t & 63;
    const int wv   = t >> 6;
    const int c    = lane & 15;
    const int g    = lane >> 4;
    char* Pw = smem + 32768 + wv * 2048;

    int bid = blockIdx.x + 16 * blockIdx.y + 128 * blockIdx.z;
    bid = (bid & 7) * 128 + (bid >> 3);
    const int q0 = (bid & 15) * 64;
    const int bh = bid >> 4;
    const int hh = bh & 7, bb = bh >> 3;
    const size_t qkb = (size_t)bh * SEQ * 128;
    const size_t vtb = (size_t)bh * 128 * SEQ;

    constexpr float SC  = 0.125f * 1.44269504f;   // scale * log2(e)
    constexpr float THR = 11.0f;                  // defer threshold (log2 units)

    bfrag qf[4];
    {
        const unsigned short* qp = Qh + qkb + (size_t)(q0 + wv * 16 + c) * 128 + g * 8;
        #pragma unroll
        for (int ks = 0; ks < 4; ++ks) qf[ks] = *(const bfrag*)(qp + ks * 32);
    }
    bfrag vones;
    #pragma unroll
    for (int j = 0; j < 8; ++j) vones[j] = (short)0x3F80;   // bf16 1.0

    f32x4 oacc[8];
    #pragma unroll
    for (int i = 0; i < 8; ++i) oacc[i] = (f32x4){0.f, 0.f, 0.f, 0.f};
    f32x4 oaccl = (f32x4){0.f, 0.f, 0.f, 0.f};   // row-sums l[q=c]
    float mrun[4];
    #pragma unroll
    for (int r = 0; r < 4; ++r) mrun[r] = -1e30f;

    const int kkey = t >> 2, kq = t & 3;
    const unsigned short* kgp = Kh + qkb + (size_t)kkey * 128 + kq * 32;
    const int vd = t >> 1, vh2 = t & 1;
    const unsigned short* vgp = Vth + vtb + (size_t)vd * SEQ + vh2 * 32;

    bfrag krg[4], vrg[4];
    #pragma unroll
    for (int j = 0; j < 4; ++j) krg[j] = *(const bfrag*)(kgp + j * 8);
    #pragma unroll
    for (int j = 0; j < 4; ++j) vrg[j] = *(const bfrag*)(vgp + j * 8);

    for (int k0 = 0; k0 < SEQ; k0 += 64) {
        __syncthreads();
        #pragma unroll
        for (int j = 0; j < 4; ++j) {
            const int boff = (kkey * 256 + (kq * 32 + j * 8) * 2) ^ ((kkey & 7) << 4);
            *(bfrag*)(Ksm + boff) = krg[j];
        }
        #pragma unroll
        for (int j = 0; j < 4; ++j) {
            const int boff = (vd * 128 + (vh2 * 32 + j * 8) * 2) ^ ((vd & 7) << 4);
            *(bfrag*)(Vsm + boff) = vrg[j];
        }
        __syncthreads();

        if (k0 + 64 < SEQ) {   // T14: next-tile loads hide under compute
            const int kn = k0 + 64;
            #pragma unroll
            for (int j = 0; j < 4; ++j) krg[j] = *(const bfrag*)(kgp + (size_t)kn * 128 + j * 8);
            #pragma unroll
            for (int j = 0; j < 4; ++j) vrg[j] = *(const bfrag*)(vgp + kn + j * 8);
        }

        // ---- S = Q̂ · K̂ᵀ
        f32x4 sa[4];
        #pragma unroll
        for (int nt = 0; nt < 4; ++nt) sa[nt] = (f32x4){0.f, 0.f, 0.f, 0.f};
        __builtin_amdgcn_s_setprio(1);
        #pragma unroll
        for (int nt = 0; nt < 4; ++nt) {
            const int key = nt * 16 + c;
            #pragma unroll
            for (int ks = 0; ks < 4; ++ks) {
                const int boff = (key * 256 + (ks * 32 + g * 8) * 2) ^ ((key & 7) << 4);
                const bfrag bk = *(const bfrag*)(Ksm + boff);
                sa[nt] = __builtin_amdgcn_mfma_f32_16x16x32_bf16(qf[ks], bk, sa[nt], 0, 0, 0);
            }
        }
        __builtin_amdgcn_s_setprio(0);

        float sv[4][4];
        #pragma unroll
        for (int nt = 0; nt < 4; ++nt)
            #pragma unroll
            for (int r = 0; r < 4; ++r) sv[nt][r] = sa[nt][r] * SC;

        // local max per row; cross-lane reduce + rescale only on refresh
        float mloc[4];
        #pragma unroll
        for (int r = 0; r < 4; ++r)
            mloc[r] = fmaxf(fmaxf(sv[0][r], sv[1][r]), fmaxf(sv[2][r], sv[3][r]));
        bool big = false;
        #pragma unroll
        for (int r = 0; r < 4; ++r) big |= (mloc[r] > mrun[r] + THR);
        if (__any(big)) {
            float mt[4], fs[4];
            #pragma unroll
            for (int r = 0; r < 4; ++r) mt[r] = mloc[r];
            #pragma unroll
            for (int m = 1; m <= 8; m <<= 1) {
                #pragma unroll
                for (int r = 0; r < 4; ++r) mt[r] = fmaxf(mt[r], __shfl_xor(mt[r], m, 64));
            }
            #pragma unroll
            for (int r = 0; r < 4; ++r) {
                const float mn = fmaxf(mrun[r], mt[r]);
                fs[r] = exp2f(mrun[r] - mn);
                mrun[r] = mn;
            }
            const int rr = c & 3;
            float vsel = fs[0];
            vsel = (rr == 1) ? fs[1] : vsel;
            vsel = (rr == 2) ? fs[2] : vsel;
            vsel = (rr == 3) ? fs[3] : vsel;
            const float fsc = __shfl(vsel, ((c >> 2) << 4) | (c & 3), 64);
            #pragma unroll
            for (int i = 0; i < 8; ++i) {
                oacc[i][0] *= fsc; oacc[i][1] *= fsc; oacc[i][2] *= fsc; oacc[i][3] *= fsc;
            }
            oaccl[0] *= fsc; oaccl[1] *= fsc; oaccl[2] *= fsc; oaccl[3] *= fsc;
        }

        #pragma unroll
        for (int nt = 0; nt < 4; ++nt) {
            const int col2 = (nt * 16 + c) * 2;
            #pragma unroll
            for (int r = 0; r < 4; ++r) {
                const float p = exp2f(sv[nt][r] - mrun[r]);
                const int qrow = 4 * g + r;
                *(unsigned short*)(Pw + ((qrow * 128 + col2) ^ ((qrow & 7) << 4))) = f2bf(p);
            }
        }

        asm volatile("s_waitcnt lgkmcnt(0)" ::: "memory");
        __builtin_amdgcn_sched_barrier(0);

        // ---- Oᵀ += V̂ᵀ · Pᵀ ; l += 1ᵀ · Pᵀ
        __builtin_amdgcn_s_setprio(1);
        #pragma unroll
        for (int k2 = 0; k2 < 2; ++k2) {
            const int kb2 = (k2 * 32 + g * 8) * 2;
            const bfrag pb = *(const bfrag*)(Pw + ((c * 128 + kb2) ^ ((c & 7) << 4)));
            #pragma unroll
            for (int mtl = 0; mtl < 8; ++mtl) {
                const int d = mtl * 16 + c;
                const bfrag va = *(const bfrag*)(Vsm + ((d * 128 + kb2) ^ ((d & 7) << 4)));
                oacc[mtl] = __builtin_amdgcn_mfma_f32_16x16x32_bf16(va, pb, oacc[mtl], 0, 0, 0);
            }
            oaccl = __builtin_amdgcn_mfma_f32_16x16x32_bf16(vones, pb, oaccl, 0, 0, 0);
        }
        __builtin_amdgcn_s_setprio(0);
    }

    // normalize: l[q=c] is lane-local (same C-layout as O)
    {
        const float ic = 1.0f / oaccl[0];
        #pragma unroll
        for (int i = 0; i < 8; ++i) {
            oacc[i][0] *= ic; oacc[i][1] *= ic; oacc[i][2] *= ic; oacc[i][3] *= ic;
        }
    }
    __syncthreads();
    float* Ox = (float*)(smem + wv * 8192);
    #pragma unroll
    for (int mtl = 0; mtl < 8; ++mtl)
        #pragma unroll
        for (int r = 0; r < 4; ++r)
            Ox[(mtl * 16 + 4 * g + r) * 16 + c] = oacc[mtl][r];
    asm volatile("s_waitcnt lgkmcnt(0)" ::: "memory");
    __builtin_amdgcn_sched_barrier(0);

    const int q = lane >> 2, qt = lane & 3;
    const int colbase = (qt >> 1) * 512 + hh * 64 + (qt & 1) * 32;
    const size_t rowm = (size_t)bb * SEQ + q0 + wv * 16 + q;
    unsigned short* dst = Ah + rowm * KHAT + colbase;
    #pragma unroll
    for (int j = 0; j < 8; ++j) {
        us4 o;
        #pragma unroll
        for (int e = 0; e < 4; ++e) o[e] = f2bf(Ox[(qt * 32 + j * 4 + e) * 16 + q]);
        *(us4*)(dst + j * 4) = o;
    }
}

// ---------------------------------------------------------------- complex LayerNorm
//  U (pre-LN linear output) now bf16 [row][1024]; fp32 state + bf16 X̂ out.
__global__ __launch_bounds__(256)
void cln_kernel(const unsigned short* __restrict__ U,
                float* __restrict__ Xr, float* __restrict__ Xi,
                unsigned short* __restrict__ Xh,
                const float* __restrict__ Grr, const float* __restrict__ Gri,
                const float* __restrict__ Gii, const float* __restrict__ Bbr,
                const float* __restrict__ Bbi)
{
    const int lane = threadIdx.x & 63;
    const int row  = blockIdx.x * 4 + (threadIdx.x >> 6);
    const size_t off = (size_t)row * DIM;
    const int c0 = lane * 4;
    const int c1 = 256 + lane * 4;

    float xr[8], xi[8];
    {
        const unsigned short* up = U + (size_t)row * KHAT;
        us4 a0 = *(const us4*)(up + c0);
        us4 a1 = *(const us4*)(up + c1);
        us4 b0 = *(const us4*)(up + 512 + c0);
        us4 b1 = *(const us4*)(up + 512 + c1);
        float t0[4], t1[4];
        f4a(*(const float4*)&Xr[off + c0], t0);
        f4a(*(const float4*)&Xr[off + c1], t1);
        #pragma unroll
        for (int j = 0; j < 4; ++j) { xr[j] = bf2f(a0[j]) + t0[j]; xr[4 + j] = bf2f(a1[j]) + t1[j]; }
        f4a(*(const float4*)&Xi[off + c0], t0);
        f4a(*(const float4*)&Xi[off + c1], t1);
        #pragma unroll
        for (int j = 0; j < 4; ++j) { xi[j] = bf2f(b0[j]) + t0[j]; xi[4 + j] = bf2f(b1[j]) + t1[j]; }
    }

    float sr = 0.f, si = 0.f, srr = 0.f, sii = 0.f, sri = 0.f;
    #pragma unroll
    for (int j = 0; j < 8; ++j) {
        sr += xr[j]; si += xi[j];
        srr = fmaf(xr[j], xr[j], srr);
        sii = fmaf(xi[j], xi[j], sii);
        sri = fmaf(xr[j], xi[j], sri);
    }
    #pragma unroll
    for (int m = 32; m >= 1; m >>= 1) {
        sr  += __shfl_xor(sr,  m, 64);
        si  += __shfl_xor(si,  m, 64);
        srr += __shfl_xor(srr, m, 64);
        sii += __shfl_xor(sii, m, 64);
        sri += __shfl_xor(sri, m, 64);
    }

    const float inv_d = 1.0f / DIM;
    const float mr = sr * inv_d, mi = si * inv_d;
    const float Vrr = srr * inv_d - mr * mr + 1e-5f;
    const float Vii = sii * inv_d - mi * mi + 1e-5f;
    const float Vri = sri * inv_d - mr * mi;
    const float s  = sqrtf(Vrr * Vii - Vri * Vri);
    const float tt = sqrtf(Vrr + Vii + 2.0f * s);
    const float ist = 1.0f / (s * tt);
    const float Wrr = (Vii + s) * ist;
    const float Wii = (Vrr + s) * ist;
    const float Wri = -Vri * ist;

    #pragma unroll
    for (int half = 0; half < 2; ++half) {
        const int c = half ? c1 : c0;
        float grr[4], gri[4], gii[4], pbr[4], pbi[4];
        f4a(*(const float4*)&Grr[c], grr);
        f4a(*(const float4*)&Gri[c], gri);
        f4a(*(const float4*)&Gii[c], gii);
        f4a(*(const float4*)&Bbr[c], pbr);
        f4a(*(const float4*)&Bbi[c], pbi);
        float outr[4], outi[4];
        #pragma unroll
        for (int j = 0; j < 4; ++j) {
            const int idx = half * 4 + j;
            const float cr = xr[idx] - mr;
            const float ci = xi[idx] - mi;
            const float hr = Wrr * cr + Wri * ci;
            const float hi = Wri * cr + Wii * ci;
            outr[j] = fmaf(grr[j], hr, fmaf(gri[j], hi, pbr[j]));
            outi[j] = fmaf(gri[j], hr, fmaf(gii[j], hi, pbi[j]));
        }
        *(float4*)&Xr[off + c] = a4f(outr);
        *(float4*)&Xi[off + c] = a4f(outi);
        us4 hr_, hi_;
        #pragma unroll
        for (int j = 0; j < 4; ++j) { hr_[j] = f2bf(outr[j]); hi_[j] = f2bf(outi[j]); }
        *(us4*)(Xh + (size_t)row * KHAT + c)       = hr_;
        *(us4*)(Xh + (size_t)row * KHAT + 512 + c) = hi_;
    }
}

// ---------------------------------------------------------------- init: copy + bf16 X̂
__global__ __launch_bounds__(256)
void init_cvt(const float* __restrict__ xr, const float* __restrict__ xi,
              float* __restrict__ outr, float* __restrict__ outi,
              unsigned short* __restrict__ Xh)
{
    const size_t i = ((size_t)blockIdx.x * 256 + threadIdx.x) * 4;
    float vr[4], vi[4];
    f4a(*(const float4*)(xr + i), vr);
    f4a(*(const float4*)(xi + i), vi);
    *(float4*)(outr + i) = a4f(vr);
    *(float4*)(outi + i) = a4f(vi);
    const size_t m = i >> 9;
    const int k = (int)(i & 511);
    us4 a, b;
    #pragma unroll
    for (int j = 0; j < 4; ++j) { a[j] = f2bf(vr[j]); b[j] = f2bf(vi[j]); }
    *(us4*)(Xh + m * KHAT + k)       = a;
    *(us4*)(Xh + m * KHAT + 512 + k) = b;
}

// ---------------------------------------------------------------- host
extern "C" void kernel_launch(void* const* d_in, const int* in_sizes, int n_in,
                              void* d_out, int out_size, void* d_ws, size_t ws_size,
                              hipStream_t stream) {
    (void)in_sizes; (void)n_in; (void)out_size; (void)ws_size;

    const float* in_xr = (const float*)d_in[0];
    const float* in_xi = (const float*)d_in[1];
    PrepArgs pa;
    pa.Wr[0] = (const float*)d_in[2];  pa.Wi[0] = (const float*)d_in[3];   // q
    pa.Wr[1] = (const float*)d_in[4];  pa.Wi[1] = (const float*)d_in[5];   // k
    pa.Wr[2] = (const float*)d_in[6];  pa.Wi[2] = (const float*)d_in[7];   // v
    pa.Wr[3] = (const float*)d_in[8];  pa.Wi[3] = (const float*)d_in[9];   // o
    pa.Wr[4] = (const float*)d_in[10]; pa.Wi[4] = (const float*)d_in[11];  // f1
    pa.Wr[5] = (const float*)d_in[12]; pa.Wi[5] = (const float*)d_in[13];  // f2
    pa.br[0] = (const float*)d_in[14]; pa.bi[0] = (const float*)d_in[15];
    pa.br[1] = (const float*)d_in[16]; pa.bi[1] = (const float*)d_in[17];
    pa.br[2] = (const float*)d_in[18]; pa.bi[2] = (const float*)d_in[19];
    pa.br[3] = (const float*)d_in[20]; pa.bi[3] = (const float*)d_in[21];
    pa.br[4] = (const float*)d_in[22]; pa.bi[4] = (const float*)d_in[23];
    pa.br[5] = (const float*)d_in[24]; pa.bi[5] = (const float*)d_in[25];
    const float* ln1_grr = (const float*)d_in[26];
    const float* ln1_gii = (const float*)d_in[27];
    const float* ln2_grr = (const float*)d_in[28];
    const float* ln2_gii = (const float*)d_in[29];
    const float* ln1_gri = (const float*)d_in[30];
    const float* ln1_br  = (const float*)d_in[31];
    const float* ln1_bi  = (const float*)d_in[32];
    const float* ln2_gri = (const float*)d_in[33];
    const float* ln2_br  = (const float*)d_in[34];
    const float* ln2_bi  = (const float*)d_in[35];

    float* outr = (float*)d_out;
    float* outi = outr + BSD;

    char* ws = (char*)d_ws;
    unsigned short* Xh  = (unsigned short*)(ws);                    // 16 MiB each
    unsigned short* Qh  = (unsigned short*)(ws + 16777216);         // Q̂ / Ĥ (FFN hidden)
    unsigned short* Kh  = (unsigned short*)(ws + 2 * 16777216);     // K̂ / U (pre-LN bf16)
    unsigned short* Vth = (unsigned short*)(ws + 3 * 16777216);     // V̂t
    unsigned short* Ah  = (unsigned short*)(ws + 4 * 16777216);     // Â
    unsigned short* Ball = (unsigned short*)(ws + 5 * 16777216);    // 6 x 2 MiB
    float* biasall = (float*)(ws + 5 * 16777216 + 12582912);        // 24 KB
    unsigned short* Uh = Kh;
    unsigned short* Hh = Qh;

    init_cvt<<<ROWS * DIM / 1024, 256, 0, stream>>>(in_xr, in_xi, outr, outi, Xh);

    const dim3 pgrid(KHAT, 6);
    const dim3 qgrid(24, ROWS / 128);           // fused QKV: 1536 blocks
    const dim3 ggrid(KHAT / 128, ROWS / 128);   // (8, 64)
    const dim3 agrid(SEQ / 64, NH, NB);
    const int  lgrid = ROWS / 4;

    for (int l = 0; l < NL; ++l) {
        const size_t bo = (size_t)l * DIM;
        prep_kernel<<<pgrid, 256, 0, stream>>>(pa, Ball, biasall, l);

        unsigned short* Bo = Ball + (size_t)3 * KHAT * KHAT;
        unsigned short* B1 = Ball + (size_t)4 * KHAT * KHAT;
        unsigned short* B2 = Ball + (size_t)5 * KHAT * KHAT;

        gemm_qkv<<<qgrid, 256, 0, stream>>>(Xh, Ball, biasall, Qh, Kh, Vth);
        attn_mfma<<<agrid, 256, 0, stream>>>(Qh, Kh, Vth, Ah);
        gemm_mfma<false><<<ggrid, 256, 0, stream>>>(Ah, Bo, biasall + 3 * KHAT, Uh);
        cln_kernel<<<lgrid, 256, 0, stream>>>(Uh, outr, outi, Xh,
                                              ln1_grr + bo, ln1_gri + bo, ln1_gii + bo,
                                              ln1_br + bo, ln1_bi + bo);
        gemm_mfma<true><<<ggrid, 256, 0, stream>>>(Xh, B1, biasall + 4 * KHAT, Hh);
        gemm_mfma<false><<<ggrid, 256, 0, stream>>>(Hh, B2, biasall + 5 * KHAT, Uh);
        cln_kernel<<<lgrid, 256, 0, stream>>>(Uh, outr, outi, Xh,
                                              ln2_grr + bo, ln2_gri + bo, ln2_gii + bo,
                                              ln2_br + bo, ln2_bi + bo);
    }
}